// Round 18
// baseline (750.559 us; speedup 1.0000x reference)
//
#include <hip/hip_runtime.h>

typedef unsigned short u16;
typedef unsigned int   u32;
typedef __attribute__((ext_vector_type(8))) __bf16 bf16x8;
typedef __attribute__((ext_vector_type(4))) float  f32x4;
typedef __attribute__((ext_vector_type(4))) u16    u16x4;

#define DEV __device__ __forceinline__

DEV float bf2f(u16 u){ union { u32 i; float f; } x; x.i = ((u32)u) << 16; return x.f; }
DEV u16 f2bf(float f){ union { float f; u32 i; } x; x.f = f;
  u32 r = x.i + 0x7fffu + ((x.i >> 16) & 1u); return (u16)(r >> 16); }

DEV void gload16(const void* g, void* l){
  __builtin_amdgcn_global_load_lds((const __attribute__((address_space(1))) void*)g,
                                   (__attribute__((address_space(3))) void*)l, 16, 0, 0);
}

// ---------------- fused weight prep + temporal LN (independent parts, one launch) ------
__global__ __launch_bounds__(256)
void wprep_k(const float* __restrict__ Ws, const float* __restrict__ Wt,
             const float* __restrict__ Wtp, const float* __restrict__ Wfc,
             u16* __restrict__ wbuf,
             const float* __restrict__ W1, u16* __restrict__ W1T,
             const float* __restrict__ W2, u16* __restrict__ W2T,
             u16* __restrict__ wtp2b,
             const float* __restrict__ x, const float* __restrict__ tlng,
             const float* __restrict__ tlnb, u16* __restrict__ ht){
  __shared__ float t[32][33];
  const int b = blockIdx.x, tid = threadIdx.x;
  if (b < 9792){
    int z = b / 576, r2 = b - z * 576;
    int c0 = (r2 % 24) * 32, r0 = (r2 / 24) * 32;
    const float* src = (z < 4)  ? Ws  + (size_t)z * 589824
                     : (z < 13) ? Wt  + (size_t)(z-4) * 589824
                     : (z < 16) ? Wtp + (size_t)(z-13) * 589824
                     : Wfc;
    u16* d = wbuf + (size_t)z * 589824;
    int tx = tid & 31, ty = tid >> 5;
    #pragma unroll
    for (int i = 0; i < 4; i++)
      t[ty + i*8][tx] = src[(size_t)(r0 + ty + i*8) * 768 + c0 + tx];
    __syncthreads();
    #pragma unroll
    for (int i = 0; i < 4; i++)
      d[(size_t)(c0 + ty + i*8) * 768 + r0 + tx] = f2bf(t[tx][ty + i*8]);
  } else if (b < 14400){
    const float* src; u16* dst; int R, C, bx, by;
    if (b < 12096){ int r = b - 9792;  src = W1; dst = W1T; R = 768;  C = 3072; bx = r % 96; by = r / 96; }
    else          { int r = b - 12096; src = W2; dst = W2T; R = 3072; C = 768;  bx = r % 24; by = r / 24; }
    int c0 = bx * 32, r0 = by * 32;
    int tx = tid & 31, ty = tid >> 5;
    #pragma unroll
    for (int i = 0; i < 4; i++)
      t[ty + i*8][tx] = src[(size_t)(r0 + ty + i*8) * C + c0 + tx];
    __syncthreads();
    #pragma unroll
    for (int i = 0; i < 4; i++)
      dst[(size_t)(c0 + ty + i*8) * R + r0 + tx] = f2bf(t[tx][ty + i*8]);
  } else if (b < 14976){
    int i = ((b - 14400) * 256 + tid) * 4;
    float4 f = *(const float4*)(Wtp + 2 * 589824 + i);
    u16x4 p; p[0] = f2bf(f.x); p[1] = f2bf(f.y); p[2] = f2bf(f.z); p[3] = f2bf(f.w);
    *(u16x4*)(wtp2b + i) = p;
  } else {
    int lane = tid & 63;
    int tok = (b - 14976) * 4 + (tid >> 6);
    int bb = tok / 3136, m = tok - bb * 3136;
    const float* fsrc = x + ((size_t)bb * 3137 + 1 + m) * 768;
    float v[12]; float s1 = 0.f, s2 = 0.f;
    #pragma unroll
    for (int i = 0; i < 3; i++){
      float4 f = *(const float4*)(fsrc + i * 256 + lane * 4);
      v[i*4+0] = f.x; v[i*4+1] = f.y; v[i*4+2] = f.z; v[i*4+3] = f.w;
    }
    #pragma unroll
    for (int i = 0; i < 12; i++){ s1 += v[i]; s2 += v[i]*v[i]; }
    #pragma unroll
    for (int off = 32; off; off >>= 1){ s1 += __shfl_xor(s1, off); s2 += __shfl_xor(s2, off); }
    float mu = s1 * (1.f/768.f);
    float rstd = rsqrtf(s2 * (1.f/768.f) - mu*mu + 1e-5f);
    #pragma unroll
    for (int i = 0; i < 3; i++){
      int c = i * 256 + lane * 4;
      float4 g4 = *(const float4*)(tlng + c);
      float4 b4 = *(const float4*)(tlnb + c);
      u16x4 pk;
      pk[0] = f2bf((v[i*4+0]-mu)*rstd*g4.x + b4.x);
      pk[1] = f2bf((v[i*4+1]-mu)*rstd*g4.y + b4.y);
      pk[2] = f2bf((v[i*4+2]-mu)*rstd*g4.z + b4.z);
      pk[3] = f2bf((v[i*4+3]-mu)*rstd*g4.w + b4.w);
      *(u16x4*)(ht + (size_t)tok * 768 + c) = pk;
    }
  }
}

// ---------------- bias fold, one WAVE per n ----------------
__global__ __launch_bounds__(256)
void bprep_k(const float* __restrict__ btp2, const u16* __restrict__ WfcT,
             const float* __restrict__ bfc, float* __restrict__ bprime,
             float* __restrict__ zb){
  int lane = threadIdx.x & 63;
  int n = blockIdx.x * 4 + (threadIdx.x >> 6);
  const u16* wr = WfcT + (size_t)n * 768 + lane * 12;
  const float* br = btp2 + lane * 12;
  float acc = 0.f;
  #pragma unroll
  for (int i = 0; i < 3; i++){
    u16x4 w = *(const u16x4*)(wr + i * 4);
    float4 b = *(const float4*)(br + i * 4);
    acc += bf2f(w[0]) * b.x + bf2f(w[1]) * b.y + bf2f(w[2]) * b.z + bf2f(w[3]) * b.w;
  }
  #pragma unroll
  for (int off = 32; off; off >>= 1) acc += __shfl_xor(acc, off);
  if (lane == 0){ bprime[n] = acc + bfc[n]; zb[n] = 0.f; }
}

// ---------------- spatial LN + vT zero-fill merged ----------------
__global__ __launch_bounds__(256)
void lnfz_k(const float* __restrict__ x, const u16* __restrict__ xt2,
            const float* __restrict__ gw, const float* __restrict__ bw,
            u16* __restrict__ out, u32* __restrict__ vzp, long nz){
  int b = blockIdx.x;
  if (b >= 3152){
    long i = (long)(b - 3152) * 256 + threadIdx.x;
    long stride = 2048L * 256;
    for (; i < nz; i += stride) vzp[i] = 0;
    return;
  }
  int lane = threadIdx.x & 63;
  int tok = b * 4 + (threadIdx.x >> 6);
  int s = tok / 197, j = tok - s * 197;
  int bb = s >> 4, tt = s & 15;
  float v[12]; float s1 = 0.f, s2 = 0.f;
  if (j == 0){
    const float* fsrc = x + (size_t)bb * 3137 * 768;
    #pragma unroll
    for (int i = 0; i < 3; i++){
      float4 f = *(const float4*)(fsrc + i * 256 + lane * 4);
      v[i*4+0] = f.x; v[i*4+1] = f.y; v[i*4+2] = f.z; v[i*4+3] = f.w;
    }
  } else {
    const u16* bsrc = xt2 + ((size_t)bb * 3136 + (size_t)(j - 1) * 16 + tt) * 768;
    #pragma unroll
    for (int i = 0; i < 3; i++){
      u16x4 p = *(const u16x4*)(bsrc + i * 256 + lane * 4);
      v[i*4+0] = bf2f(p[0]); v[i*4+1] = bf2f(p[1]); v[i*4+2] = bf2f(p[2]); v[i*4+3] = bf2f(p[3]);
    }
  }
  #pragma unroll
  for (int i = 0; i < 12; i++){ s1 += v[i]; s2 += v[i]*v[i]; }
  #pragma unroll
  for (int off = 32; off; off >>= 1){ s1 += __shfl_xor(s1, off); s2 += __shfl_xor(s2, off); }
  float mu = s1 * (1.f/768.f);
  float rstd = rsqrtf(s2 * (1.f/768.f) - mu*mu + 1e-5f);
  #pragma unroll
  for (int i = 0; i < 3; i++){
    int c = i * 256 + lane * 4;
    float4 g4 = *(const float4*)(gw + c);
    float4 b4 = *(const float4*)(bw + c);
    u16x4 pk;
    pk[0] = f2bf((v[i*4+0]-mu)*rstd*g4.x + b4.x);
    pk[1] = f2bf((v[i*4+1]-mu)*rstd*g4.y + b4.y);
    pk[2] = f2bf((v[i*4+2]-mu)*rstd*g4.z + b4.z);
    pk[3] = f2bf((v[i*4+3]-mu)*rstd*g4.w + b4.w);
    *(u16x4*)(out + (size_t)tok * 768 + c) = pk;
  }
}

// ---------------- final LN: reads bf16 xn ----------------
__global__ __launch_bounds__(256)
void ln2_k(const u16* __restrict__ xnb, const float* __restrict__ gw,
           const float* __restrict__ bw, u16* __restrict__ out){
  int lane = threadIdx.x & 63;
  int tok = blockIdx.x * 4 + (threadIdx.x >> 6);
  const u16* bsrc = xnb + (size_t)tok * 768;
  float v[12]; float s1 = 0.f, s2 = 0.f;
  #pragma unroll
  for (int i = 0; i < 3; i++){
    u16x4 p = *(const u16x4*)(bsrc + i * 256 + lane * 4);
    v[i*4+0] = bf2f(p[0]); v[i*4+1] = bf2f(p[1]); v[i*4+2] = bf2f(p[2]); v[i*4+3] = bf2f(p[3]);
  }
  #pragma unroll
  for (int i = 0; i < 12; i++){ s1 += v[i]; s2 += v[i]*v[i]; }
  #pragma unroll
  for (int off = 32; off; off >>= 1){ s1 += __shfl_xor(s1, off); s2 += __shfl_xor(s2, off); }
  float mu = s1 * (1.f/768.f);
  float rstd = rsqrtf(s2 * (1.f/768.f) - mu*mu + 1e-5f);
  #pragma unroll
  for (int i = 0; i < 3; i++){
    int c = i * 256 + lane * 4;
    float4 g4 = *(const float4*)(gw + c);
    float4 b4 = *(const float4*)(bw + c);
    u16x4 pk;
    pk[0] = f2bf((v[i*4+0]-mu)*rstd*g4.x + b4.x);
    pk[1] = f2bf((v[i*4+1]-mu)*rstd*g4.y + b4.y);
    pk[2] = f2bf((v[i*4+2]-mu)*rstd*g4.z + b4.z);
    pk[3] = f2bf((v[i*4+3]-mu)*rstd*g4.w + b4.w);
    *(u16x4*)(out + (size_t)tok * 768 + c) = pk;
  }
}

// ---------------- GEMM: C = Amap @ Bw^T(+bias), quad-tile, bf16 MFMA ----------------
// TILE=0: 128x128xBK32/256thr; TILE=1: 256x128xBK32/512thr; TILE=2: 64x128xBK32/256thr
// (small-K grid-starved); TILE=3: 128x128xBK64/256thr (large-K: halves barrier count,
// LDS 64KB -> 2 blocks/CU; grid-capped dispatches unaffected by the occupancy drop).
// Generalized staging: NA/NB 16B-slots per thread, CH = BK/8 chunks per row.
// MODE 0 bf16 | 1 blend RMW | 2 bf16 +f32 residual | 3 spatial scatter->bf16 xn (+cls)
// MODE 4 gelu | 5 f32 = val + bf16 xn | 8 temporal QKV | 9 spatial QKV (shifted vT)
template<int MODE, int TILE>
__global__ __launch_bounds__(TILE == 1 ? 512 : 256, TILE == 2 ? 5 : (TILE == 3 ? 2 : 4))
void gemm_k(const u16* __restrict__ A, const u16* __restrict__ Bw,
            const float* __restrict__ bias, void* out,
            const void* aux1, void* aux2, int nbx,
            int M, int K, int lda, int ldo,
            int aTs, int aTf, int at0, int oTs, int oTf, int ot0){
  constexpr int BM = (TILE == 1) ? 256 : (TILE == 2 ? 64 : 128);
  constexpr int BK = (TILE == 3) ? 64 : 32;
  constexpr int THREADS = (TILE == 1) ? 512 : 256;
  constexpr int IM = (TILE == 2) ? 2 : 4;
  constexpr int WSPAN = IM * 16;
  constexpr int CH = BK / 8;                       // 16B chunks per row
  constexpr int NA = BM * BK / 8 / THREADS;        // A slots per thread
  constexpr int NB = 128 * BK / 8 / THREADS;       // B slots per thread
  __shared__ u16 lA[2][BM * BK];
  __shared__ u16 lB[2][128 * BK];
  const int tid = threadIdx.x;

  const int nwg = (int)gridDim.x;
  int id = (int)blockIdx.x;
  int qc = nwg >> 3, rc = nwg & 7;
  int xcd = id & 7, off = id >> 3;
  int wg = (xcd < rc ? xcd * (qc + 1) : rc * (qc + 1) + (xcd - rc) * qc) + off;
  int by = wg / nbx;
  int bx = wg - by * nbx;
  const int m0 = by * BM, n0 = bx * 128;

  const int lane = tid & 63, widx = tid >> 6;
  const int g = lane >> 4, r16 = lane & 15;
  const int wm = widx >> 1, wn = widx & 1;

  const u16* ga[NA]; u32 loA[NA];
  const u16* gb[NB]; u32 loB[NB];
  #pragma unroll
  for (int s = 0; s < NA; s++){
    int li = tid + s * THREADS;
    int ar = m0 + li / CH; if (ar > M - 1) ar = M - 1;
    ar = (ar / aTs) * aTf + at0 + (ar % aTs);
    ga[s] = A + (size_t)ar * lda + (li % CH) * 8;
    loA[s] = li * 8;
  }
  #pragma unroll
  for (int s = 0; s < NB; s++){
    int li = tid + s * THREADS;
    gb[s] = Bw + (size_t)(n0 + li / CH) * K + (li % CH) * 8;
    loB[s] = li * 8;
  }

  const f32x4 vz = {0.f, 0.f, 0.f, 0.f};
  f32x4 acc[IM][4];
  #pragma unroll
  for (int i = 0; i < IM; i++)
    #pragma unroll
    for (int j = 0; j < 4; j++) acc[i][j] = vz;

  const int kiter = K / BK;

  #pragma unroll
  for (int s = 0; s < NA; s++) gload16(ga[s], &lA[0][loA[s]]);
  #pragma unroll
  for (int s = 0; s < NB; s++) gload16(gb[s], &lB[0][loB[s]]);
  #pragma unroll
  for (int s = 0; s < NA; s++) ga[s] += BK;
  #pragma unroll
  for (int s = 0; s < NB; s++) gb[s] += BK;
  __syncthreads();

  for (int kt = 0; kt < kiter; ++kt){
    const int cur = kt & 1;
    if (kt + 1 < kiter){
      const int nxt = cur ^ 1;
      #pragma unroll
      for (int s = 0; s < NA; s++) gload16(ga[s], &lA[nxt][loA[s]]);
      #pragma unroll
      for (int s = 0; s < NB; s++) gload16(gb[s], &lB[nxt][loB[s]]);
      #pragma unroll
      for (int s = 0; s < NA; s++) ga[s] += BK;
      #pragma unroll
      for (int s = 0; s < NB; s++) gb[s] += BK;
    }
    #pragma unroll
    for (int kk = 0; kk < BK / 32; ++kk){
      bf16x8 af[IM], bfr[4];
      #pragma unroll
      for (int i = 0; i < IM; i++)
        af[i]  = *(const bf16x8*)(&lA[cur][(wm * WSPAN + i * 16 + r16) * BK + kk * 32 + g * 8]);
      #pragma unroll
      for (int j = 0; j < 4; j++)
        bfr[j] = *(const bf16x8*)(&lB[cur][(wn * 64 + j * 16 + r16) * BK + kk * 32 + g * 8]);
      #pragma unroll
      for (int i = 0; i < IM; i++)
        #pragma unroll
        for (int j = 0; j < 4; j++)
          acc[i][j] = __builtin_amdgcn_mfma_f32_16x16x32_bf16(af[i], bfr[j], acc[i][j], 0, 0, 0);
    }
    __syncthreads();
  }

  #pragma unroll
  for (int i = 0; i < IM; i++){
    const int lrow = wm * WSPAN + i * 16 + g * 4;
    #pragma unroll
    for (int j = 0; j < 4; j++){
      const int Cg = n0 + wn * 64 + j * 16 + r16;
      const float b0 = bias[Cg];
      float vv[4];
      #pragma unroll
      for (int r = 0; r < 4; r++) vv[r] = acc[i][j][r] + b0;

      if constexpr (MODE == 8){
        int mat = Cg / 768, c0 = Cg - mat * 768;
        if (mat < 2){
          #pragma unroll
          for (int r = 0; r < 4; r++){
            int R = m0 + lrow + r;
            if (R < M)
              ((u16*)out)[(size_t)mat * ot0 * 768 + (size_t)R * 768 + c0] = f2bf(vv[r]);
          }
        } else {
          int R0 = m0 + lrow;
          if (R0 < M){
            int seq_ = R0 / oTs, t0 = R0 - seq_ * oTs;
            u16x4 pk;
            #pragma unroll
            for (int r = 0; r < 4; r++) pk[r] = f2bf(vv[r]);
            *(u16x4*)((u16*)aux2 +
              ((size_t)(seq_ * 12 + (c0 >> 6)) * 64 + (c0 & 63)) * ldo + t0) = pk;
          }
        }
      } else if constexpr (MODE == 9){
        int mat = Cg / 768, c0 = Cg - mat * 768;
        if (mat < 2){
          #pragma unroll
          for (int r = 0; r < 4; r++){
            int R = m0 + lrow + r;
            if (R < M)
              ((u16*)out)[(size_t)mat * ot0 * 768 + (size_t)R * 768 + c0] = f2bf(vv[r]);
          }
        } else {
          int R0 = m0 + lrow;
          if (R0 < M){
            int s_ = R0 / 197, j0 = R0 - s_ * 197;
            if (j0 <= 193){
              u16x4 pk;
              #pragma unroll
              for (int r = 0; r < 4; r++) pk[r] = f2bf(vv[r]);
              *(u16x4*)((u16*)aux2 +
                ((size_t)(s_ * 12 + (c0 >> 6)) * 64 + (c0 & 63)) * 224 + j0 + (s_ & 3)) = pk;
            } else {
              #pragma unroll
              for (int r = 0; r < 4; r++){
                int R = R0 + r;
                if (R < M){
                  int s2 = R / 197, j2 = R - s2 * 197;
                  ((u16*)aux2)[((size_t)(s2 * 12 + (c0 >> 6)) * 64 + (c0 & 63)) * 224
                               + j2 + (s2 & 3)] = f2bf(vv[r]);
                }
              }
            }
          }
        }
      } else {
        #pragma unroll
        for (int r = 0; r < 4; r++){
          const int R = m0 + lrow + r;
          if (R >= M) continue;
          float val = vv[r];
          if constexpr (MODE == 0){
            ((u16*)out)[(size_t)R * ldo + Cg] = f2bf(val);
          } else if constexpr (MODE == 1){
            int Ro = (R / oTs) * oTf + ot0 + (R % oTs);
            u16* po = (u16*)out + (size_t)Ro * ldo + Cg;
            *po = f2bf(0.5f * val + 0.5f * bf2f(*po));
          } else if constexpr (MODE == 2){
            int b_ = R / 3136, m_ = R - b_ * 3136;
            ((u16*)out)[(size_t)R * 768 + Cg] =
                f2bf(val + ((const float*)aux1)[((size_t)b_ * 3137 + 1 + m_) * 768 + Cg]);
          } else if constexpr (MODE == 3){
            int s_ = R / 197, j_ = R - s_ * 197;
            if (j_ == 0){
              ((float*)aux2)[(size_t)s_ * 768 + Cg] = val;
            } else {
              int b_ = s_ >> 4, t_ = s_ & 15, m_ = (j_ - 1) * 16 + t_;
              ((u16*)out)[((size_t)b_ * 3137 + 1 + m_) * 768 + Cg] =
                  f2bf(val + bf2f(((const u16*)aux1)[((size_t)b_ * 3136 + m_) * 768 + Cg]));
            }
          } else if constexpr (MODE == 4){
            float c = val * (0.7978845608f + 0.0356774081f * val * val);
            float e2 = __expf(2.f * fabsf(c));
            float th = __builtin_copysignf(1.f - 2.f / (e2 + 1.f), c);
            ((u16*)out)[(size_t)R * ldo + Cg] = f2bf(0.5f * val * (1.f + th));
          } else if constexpr (MODE == 5){
            ((float*)out)[(size_t)R * 768 + Cg] =
                val + bf2f(((const u16*)aux1)[(size_t)R * 768 + Cg]);
          }
        }
      }
    }
  }
}

// ---------------- temporal attention via MFMA: one wave per (seq,head) ----------------
template<int TS, int TSPAD>
__global__ __launch_bounds__(256)
void tattn_k(const u16* __restrict__ q, const u16* __restrict__ k,
             const u16* __restrict__ vt, u16* __restrict__ o){
  const int lane = threadIdx.x & 63;
  const int g = lane >> 4, r16 = lane & 15;
  int p = blockIdx.x * 4 + (threadIdx.x >> 6);
  int seq = p / 12, h = p - seq * 12;

  int trow = (TS < 16 && r16 >= TS) ? TS - 1 : r16;
  size_t qko = (size_t)(seq * TS + trow) * 768 + h * 64 + g * 8;
  bf16x8 ak0 = *(const bf16x8*)(k + qko);
  bf16x8 ak1 = *(const bf16x8*)(k + qko + 32);
  bf16x8 bq0 = *(const bf16x8*)(q + qko);
  bf16x8 bq1 = *(const bf16x8*)(q + qko + 32);

  f32x4 s = {0.f, 0.f, 0.f, 0.f};
  s = __builtin_amdgcn_mfma_f32_16x16x32_bf16(ak0, bq0, s, 0, 0, 0);
  s = __builtin_amdgcn_mfma_f32_16x16x32_bf16(ak1, bq1, s, 0, 0, 0);

  const float C = 0.125f * 1.44269504089f;
  float pv[4]; float mx = -3e38f;
  #pragma unroll
  for (int r = 0; r < 4; r++){
    float x = (g * 4 + r < TS) ? s[r] : -3e38f;
    pv[r] = x; mx = fmaxf(mx, x);
  }
  mx = fmaxf(mx, __shfl_xor(mx, 16));
  mx = fmaxf(mx, __shfl_xor(mx, 32));
  float sum = 0.f;
  #pragma unroll
  for (int r = 0; r < 4; r++){ pv[r] = exp2f((pv[r] - mx) * C); sum += pv[r]; }
  sum += __shfl_xor(sum, 16);
  sum += __shfl_xor(sum, 32);
  float inv = 1.f / sum;
  #pragma unroll
  for (int r = 0; r < 4; r++) pv[r] *= inv;

  u32 w0 = (u32)f2bf(pv[0]) | ((u32)f2bf(pv[1]) << 16);
  u32 w1 = (u32)f2bf(pv[2]) | ((u32)f2bf(pv[3]) << 16);
  int a0 = ((g * 2) * 16 + r16) * 4;
  int a1 = ((g * 2 + 1) * 16 + r16) * 4;
  u32 msk = (g < 2) ? 0xFFFFFFFFu : 0u;
  union { u32 w[4]; bf16x8 v; } pa;
  pa.w[0] = msk & (u32)__builtin_amdgcn_ds_bpermute(a0, (int)w0);
  pa.w[1] = msk & (u32)__builtin_amdgcn_ds_bpermute(a0, (int)w1);
  pa.w[2] = msk & (u32)__builtin_amdgcn_ds_bpermute(a1, (int)w0);
  pa.w[3] = msk & (u32)__builtin_amdgcn_ds_bpermute(a1, (int)w1);

  const u16* vb = vt + ((size_t)(seq * 12 + h) * 64) * TSPAD;
  const f32x4 vz = {0.f, 0.f, 0.f, 0.f};
  f32x4 oc[4];
  #pragma unroll
  for (int dt = 0; dt < 4; ++dt){
    bf16x8 bv = *(const bf16x8*)(vb + (size_t)(dt * 16 + r16) * TSPAD + g * 8);
    oc[dt] = __builtin_amdgcn_mfma_f32_16x16x32_bf16(pa.v, bv, vz, 0, 0, 0);
  }
  #pragma unroll
  for (int rr = 0; rr < 4; ++rr){
    int qr = g * 4 + rr;
    if (qr < TS){
      size_t ob = (size_t)(seq * TS + qr) * 768 + h * 64 + r16;
      #pragma unroll
      for (int dt = 0; dt < 4; ++dt)
        o[ob + dt * 16] = f2bf(oc[dt][rr]);
    }
  }
}

// ---------------- spatial attention: 4 waves/block ----------------
__global__ __launch_bounds__(256)
void sattn_k(const u16* __restrict__ qs, const u16* __restrict__ ks,
             const u16* __restrict__ vt, u16* __restrict__ o){
  __shared__ u16 PlAll[4][16 * 224];
  const int wid = threadIdx.x >> 6;
  u16* Pl = PlAll[wid];
  const int lane = threadIdx.x & 63;
  const int g = lane >> 4, r16 = lane & 15;
  int gi = blockIdx.x * 4 + wid;
  int chunk = gi % 13; int sh_ = gi / 13;
  int h = sh_ % 12, s = sh_ / 12;
  const int shft = s & 3;
  const float sc_l2e = 0.125f * 1.44269504089f;

  #pragma unroll
  for (int i = 0; i < 4; i++){
    Pl[(i * 4 + g) * 224 + 208 + r16] = 0;
    if (r16 < 4) Pl[(i * 4 + g) * 224 + r16] = 0;
  }

  int q0 = chunk * 16;
  int qrow = q0 + r16; if (qrow > 196) qrow = 196;
  const u16* qp = qs + ((size_t)(s * 197 + qrow)) * 768 + h * 64 + g * 8;
  bf16x8 aq0 = *(const bf16x8*)qp;
  bf16x8 aq1 = *(const bf16x8*)(qp + 32);

  f32x4 scv[13];
  #pragma unroll
  for (int jt = 0; jt < 13; ++jt){
    int krow = jt * 16 + r16; if (krow > 196) krow = 196;
    const u16* kp = ks + ((size_t)(s * 197 + krow)) * 768 + h * 64 + g * 8;
    bf16x8 b0 = *(const bf16x8*)kp;
    bf16x8 b1 = *(const bf16x8*)(kp + 32);
    f32x4 z = {0.f, 0.f, 0.f, 0.f};
    z = __builtin_amdgcn_mfma_f32_16x16x32_bf16(aq0, b0, z, 0, 0, 0);
    z = __builtin_amdgcn_mfma_f32_16x16x32_bf16(aq1, b1, z, 0, 0, 0);
    scv[jt] = z;
  }
  float mrow[4] = {-3e38f, -3e38f, -3e38f, -3e38f};
  #pragma unroll
  for (int jt = 0; jt < 13; ++jt)
    #pragma unroll
    for (int r = 0; r < 4; r++){
      float x = (jt * 16 + r16 < 197) ? scv[jt][r] : -3e38f;
      scv[jt][r] = x;
      mrow[r] = fmaxf(mrow[r], x);
    }
  #pragma unroll
  for (int off = 1; off < 16; off <<= 1)
    #pragma unroll
    for (int r = 0; r < 4; r++) mrow[r] = fmaxf(mrow[r], __shfl_xor(mrow[r], off));
  float srow[4] = {0.f, 0.f, 0.f, 0.f};
  #pragma unroll
  for (int jt = 0; jt < 13; ++jt)
    #pragma unroll
    for (int r = 0; r < 4; r++){
      float e = exp2f((scv[jt][r] - mrow[r]) * sc_l2e);
      scv[jt][r] = e;
      srow[r] += e;
    }
  #pragma unroll
  for (int off = 1; off < 16; off <<= 1)
    #pragma unroll
    for (int r = 0; r < 4; r++) srow[r] += __shfl_xor(srow[r], off);
  float inv[4];
  #pragma unroll
  for (int r = 0; r < 4; r++) inv[r] = 1.f / srow[r];
  #pragma unroll
  for (int jt = 0; jt < 13; ++jt)
    #pragma unroll
    for (int r = 0; r < 4; r++)
      Pl[(g * 4 + r) * 224 + jt * 16 + r16 + shft] = f2bf(scv[jt][r] * inv[r]);
  __syncthreads();
  const u16* vbase = vt + ((size_t)(s * 12 + h) * 64) * 224;
  f32x4 oc[4]; const f32x4 vz = {0.f,0.f,0.f,0.f};
  #pragma unroll
  for (int dt = 0; dt < 4; dt++) oc[dt] = vz;
  #pragma unroll
  for (int ks2 = 0; ks2 < 7; ++ks2){
    bf16x8 ap = *(const bf16x8*)(Pl + r16 * 224 + ks2 * 32 + g * 8);
    #pragma unroll
    for (int dt = 0; dt < 4; ++dt){
      const u16* vp = vbase + ((size_t)(dt * 16 + r16)) * 224 + ks2 * 32 + g * 8;
      bf16x8 bv = *(const bf16x8*)vp;
      oc[dt] = __builtin_amdgcn_mfma_f32_16x16x32_bf16(ap, bv, oc[dt], 0, 0, 0);
    }
  }
  #pragma unroll
  for (int dt = 0; dt < 4; ++dt)
    #pragma unroll
    for (int r = 0; r < 4; r++){
      int qr2 = q0 + g * 4 + r;
      if (qr2 < 197)
        o[((size_t)(s * 197 + qr2)) * 768 + h * 64 + dt * 16 + r16] = f2bf(oc[dt][r]);
    }
}

// ---------------- cls row: xn[b,0] = bf16(x[b,0] + mean_t clsbuf[b*16+t]) --------------
__global__ __launch_bounds__(256)
void clsfin_k(const float* __restrict__ x, const float* __restrict__ cb, u16* __restrict__ xn){
  int b = blockIdx.x;
  int c = blockIdx.y * 256 + threadIdx.x;
  float s = 0.f;
  #pragma unroll
  for (int t = 0; t < 16; t++) s += cb[((size_t)(b * 16 + t)) * 768 + c];
  xn[(size_t)b * 3137 * 768 + c] = f2bf(x[(size_t)b * 3137 * 768 + c] + s * (1.f / 16.f));
}

// ======================================================================================
extern "C" void kernel_launch(void* const* d_in, const int* in_sizes, int n_in,
                              void* d_out, int out_size, void* d_ws, size_t ws_size,
                              hipStream_t stream){
  (void)in_sizes; (void)n_in; (void)out_size;
  const float* x    = (const float*)d_in[0];
  const float* ln1g = (const float*)d_in[1];
  const float* ln1b = (const float*)d_in[2];
  const float* tlng = (const float*)d_in[3];
  const float* tlnb = (const float*)d_in[4];
  const float* ln2g = (const float*)d_in[5];
  const float* ln2b = (const float*)d_in[6];
  const float* Ws   = (const float*)d_in[7];
  const float* bs   = (const float*)d_in[8];
  const float* Wt   = (const float*)d_in[9];
  const float* bt   = (const float*)d_in[10];
  const float* Wtp  = (const float*)d_in[11];
  const float* btp  = (const float*)d_in[12];
  const float* Wfc  = (const float*)d_in[13];
  const float* bfc  = (const float*)d_in[14];
  const float* W1   = (const float*)d_in[15];
  const float* b1   = (const float*)d_in[16];
  const float* W2   = (const float*)d_in[17];
  const float* b2   = (const float*)d_in[18];
  float* out = (float*)d_out;

  constexpr size_t MiB = 1048576;
  constexpr size_t C2  = 589824;
  constexpr size_t W_BYTES = (17 * C2 + 2 * 2359296) * 2;  // 29,491,200
  constexpr size_t NEED = W_BYTES + 143 * MiB;
  if (ws_size < NEED) return;

  char* wsb  = (char*)d_ws;
  u16*  wbuf = (u16*)wsb;
  u16*  W1T  = wbuf + 17 * C2;
  u16*  W2T  = W1T + (size_t)3072 * 768;
  char* A0   = wsb + W_BYTES;

  u16*  ht  = (u16*)(A0 + 0   * MiB);
  u16*  qk  = (u16*)(A0 + 20  * MiB);
  u16*  vtb = (u16*)(A0 + 58  * MiB);
  u16*  o16 = (u16*)(A0 + 86  * MiB);
  u16*  o8  = (u16*)(A0 + 105 * MiB);
  u16*  o4  = (u16*)(A0 + 115 * MiB);
  u16*  xt2 = (u16*)(A0 + 105 * MiB);
  u16*  xnb = (u16*)(A0 + 20 * MiB);
  u16*  wtp2b = (u16*)(A0 + 132 * MiB);
  u16*  WpT   = (u16*)(A0 + 134 * MiB);
  float* bprime = (float*)(A0 + 136 * MiB);
  float* zb     = bprime + 1024;
  float* clsb = (float*)(A0 + 142 * MiB);
  u16*  hs  = ht;  u16* osb = ht; u16* h2 = ht;
  u16*  a1  = (u16*)(A0 + 58 * MiB);

  // -- fused weight prep + temporal LN, bias fold, W' GEMM
  wprep_k<<<18112, 256, 0, stream>>>(Ws, Wt, Wtp, Wfc, wbuf, W1, W1T, W2, W2T,
                                     wtp2b, x, tlng, tlnb, ht);
  bprep_k<<<192, 256, 0, stream>>>(btp + 1536, wbuf + 16*C2, bfc, bprime, zb);
  gemm_k<0,2><<<12*6, 256, 0, stream>>>(wbuf + 16*C2, wtp2b, zb, WpT, nullptr, nullptr, 6, 768, 768, 768, 768, 1,1,0, 1,1,0);

  // -- scale 16: fused QKV + attn  [BIG tile]
  gemm_k<8,1><<<49*18, 512, 0, stream>>>(ht, wbuf + 10*C2, bt + 6*768, qk, nullptr, vtb, 18, 12544, 768, 768, 24, 1,1,0, 16,1,12544);
  tattn_k<16,24><<<2352, 256, 0, stream>>>(qk, qk + (size_t)12544*768, vtb, o16);

  // -- scale 8  [thin tile, K=768]
  gemm_k<8,2><<<98*18, 256, 0, stream>>>(ht, wbuf +  7*C2, bt + 3*768, qk, nullptr, vtb, 18, 6272, 768, 768, 16, 8,16,8, 8,1,6272);
  tattn_k< 8,16><<<2352, 256, 0, stream>>>(qk, qk + (size_t)6272*768, vtb, o8);

  // -- scale 4  [thin tile, K=768]
  gemm_k<8,2><<<49*18, 256, 0, stream>>>(ht, wbuf +  4*C2, bt + 0*768, qk, nullptr, vtb, 18, 3136, 768, 768, 16, 4,16,12, 4,1,3136);
  tattn_k< 4,16><<<2352, 256, 0, stream>>>(qk, qk + (size_t)3136*768, vtb, o4);

  // -- blend chain + collapsed xt2  [thin tile, K=768]
  gemm_k<1,2><<<49*6, 256, 0, stream>>>(o4,  wbuf + 13*C2, btp + 0,   o8,  nullptr, nullptr, 6, 3136, 768, 768, 768, 1,1,0, 4,8,4);
  gemm_k<1,2><<<98*6, 256, 0, stream>>>(o8,  wbuf + 14*C2, btp + 768, o16, nullptr, nullptr, 6, 6272, 768, 768, 768, 1,1,0, 8,16,8);
  gemm_k<2,2><<<196*6, 256, 0, stream>>>(o16, WpT,         bprime,    xt2, x, nullptr,       6, 12544, 768, 768, 768, 1,1,0, 1,1,0);

  // -- spatial LN + vT zero-fill, fused QKV  [BIG tile]
  lnfz_k<<<5200, 256, 0, stream>>>(x, xt2, ln1g, ln1b, hs, (u32*)vtb, 5505024);
  gemm_k<9,1><<<50*18, 512, 0, stream>>>(hs, wbuf + 0*C2, bs + 0, qk, nullptr, vtb, 18, 12608, 768, 768, 224, 1,1,0, 1,1,12608);

  // -- spatial attention
  sattn_k<<<2496, 256, 0, stream>>>(qk, qk + (size_t)12608*768, vtb, osb);

  // -- spatial proj + residual scatter  [thin tile, K=768]
  gemm_k<3,2><<<197*6, 256, 0, stream>>>(osb, wbuf + 3*C2, bs + 2304, xnb, xt2, clsb, 6, 12608, 768, 768, 768, 1,1,0, 1,1,0);
  clsfin_k<<<dim3(4, 3), 256, 0, stream>>>(x, clsb, xnb);

  // -- final LN + MLP  [up: BIG; down: BK=64 tile (K=3072: halve barrier count)]
  ln2_k<<<3137, 256, 0, stream>>>(xnb, ln2g, ln2b, h2);
  gemm_k<4,1><<<50*24, 512, 0, stream>>>(h2, W1T, b1, a1,  nullptr, nullptr, 24, 12548, 768, 768, 3072, 1,1,0, 1,1,0);
  gemm_k<5,3><<<99*6, 256, 0, stream>>>(a1, W2T, b2, out, xnb, nullptr,      6, 12548, 3072, 3072, 768, 1,1,0, 1,1,0);
}

// Round 19
// 678.832 us; speedup vs baseline: 1.1057x; 1.1057x over previous
//
#include <hip/hip_runtime.h>

typedef unsigned short u16;
typedef unsigned int   u32;
typedef __attribute__((ext_vector_type(8))) __bf16 bf16x8;
typedef __attribute__((ext_vector_type(4))) float  f32x4;
typedef __attribute__((ext_vector_type(4))) u16    u16x4;

#define DEV __device__ __forceinline__

DEV float bf2f(u16 u){ union { u32 i; float f; } x; x.i = ((u32)u) << 16; return x.f; }
DEV u16 f2bf(float f){ union { float f; u32 i; } x; x.f = f;
  u32 r = x.i + 0x7fffu + ((x.i >> 16) & 1u); return (u16)(r >> 16); }

DEV void gload16(const void* g, void* l){
  __builtin_amdgcn_global_load_lds((const __attribute__((address_space(1))) void*)g,
                                   (__attribute__((address_space(3))) void*)l, 16, 0, 0);
}

// ---------------- fused weight prep + temporal LN (independent parts, one launch) ------
__global__ __launch_bounds__(256)
void wprep_k(const float* __restrict__ Ws, const float* __restrict__ Wt,
             const float* __restrict__ Wtp, const float* __restrict__ Wfc,
             u16* __restrict__ wbuf,
             const float* __restrict__ W1, u16* __restrict__ W1T,
             const float* __restrict__ W2, u16* __restrict__ W2T,
             u16* __restrict__ wtp2b,
             const float* __restrict__ x, const float* __restrict__ tlng,
             const float* __restrict__ tlnb, u16* __restrict__ ht){
  __shared__ float t[32][33];
  const int b = blockIdx.x, tid = threadIdx.x;
  if (b < 9792){
    int z = b / 576, r2 = b - z * 576;
    int c0 = (r2 % 24) * 32, r0 = (r2 / 24) * 32;
    const float* src = (z < 4)  ? Ws  + (size_t)z * 589824
                     : (z < 13) ? Wt  + (size_t)(z-4) * 589824
                     : (z < 16) ? Wtp + (size_t)(z-13) * 589824
                     : Wfc;
    u16* d = wbuf + (size_t)z * 589824;
    int tx = tid & 31, ty = tid >> 5;
    #pragma unroll
    for (int i = 0; i < 4; i++)
      t[ty + i*8][tx] = src[(size_t)(r0 + ty + i*8) * 768 + c0 + tx];
    __syncthreads();
    #pragma unroll
    for (int i = 0; i < 4; i++)
      d[(size_t)(c0 + ty + i*8) * 768 + r0 + tx] = f2bf(t[tx][ty + i*8]);
  } else if (b < 14400){
    const float* src; u16* dst; int R, C, bx, by;
    if (b < 12096){ int r = b - 9792;  src = W1; dst = W1T; R = 768;  C = 3072; bx = r % 96; by = r / 96; }
    else          { int r = b - 12096; src = W2; dst = W2T; R = 3072; C = 768;  bx = r % 24; by = r / 24; }
    int c0 = bx * 32, r0 = by * 32;
    int tx = tid & 31, ty = tid >> 5;
    #pragma unroll
    for (int i = 0; i < 4; i++)
      t[ty + i*8][tx] = src[(size_t)(r0 + ty + i*8) * C + c0 + tx];
    __syncthreads();
    #pragma unroll
    for (int i = 0; i < 4; i++)
      dst[(size_t)(c0 + ty + i*8) * R + r0 + tx] = f2bf(t[tx][ty + i*8]);
  } else if (b < 14976){
    int i = ((b - 14400) * 256 + tid) * 4;
    float4 f = *(const float4*)(Wtp + 2 * 589824 + i);
    u16x4 p; p[0] = f2bf(f.x); p[1] = f2bf(f.y); p[2] = f2bf(f.z); p[3] = f2bf(f.w);
    *(u16x4*)(wtp2b + i) = p;
  } else {
    int lane = tid & 63;
    int tok = (b - 14976) * 4 + (tid >> 6);
    int bb = tok / 3136, m = tok - bb * 3136;
    const float* fsrc = x + ((size_t)bb * 3137 + 1 + m) * 768;
    float v[12]; float s1 = 0.f, s2 = 0.f;
    #pragma unroll
    for (int i = 0; i < 3; i++){
      float4 f = *(const float4*)(fsrc + i * 256 + lane * 4);
      v[i*4+0] = f.x; v[i*4+1] = f.y; v[i*4+2] = f.z; v[i*4+3] = f.w;
    }
    #pragma unroll
    for (int i = 0; i < 12; i++){ s1 += v[i]; s2 += v[i]*v[i]; }
    #pragma unroll
    for (int off = 32; off; off >>= 1){ s1 += __shfl_xor(s1, off); s2 += __shfl_xor(s2, off); }
    float mu = s1 * (1.f/768.f);
    float rstd = rsqrtf(s2 * (1.f/768.f) - mu*mu + 1e-5f);
    #pragma unroll
    for (int i = 0; i < 3; i++){
      int c = i * 256 + lane * 4;
      float4 g4 = *(const float4*)(tlng + c);
      float4 b4 = *(const float4*)(tlnb + c);
      u16x4 pk;
      pk[0] = f2bf((v[i*4+0]-mu)*rstd*g4.x + b4.x);
      pk[1] = f2bf((v[i*4+1]-mu)*rstd*g4.y + b4.y);
      pk[2] = f2bf((v[i*4+2]-mu)*rstd*g4.z + b4.z);
      pk[3] = f2bf((v[i*4+3]-mu)*rstd*g4.w + b4.w);
      *(u16x4*)(ht + (size_t)tok * 768 + c) = pk;
    }
  }
}

// ---------------- bias fold, one WAVE per n ----------------
__global__ __launch_bounds__(256)
void bprep_k(const float* __restrict__ btp2, const u16* __restrict__ WfcT,
             const float* __restrict__ bfc, float* __restrict__ bprime,
             float* __restrict__ zb){
  int lane = threadIdx.x & 63;
  int n = blockIdx.x * 4 + (threadIdx.x >> 6);
  const u16* wr = WfcT + (size_t)n * 768 + lane * 12;
  const float* br = btp2 + lane * 12;
  float acc = 0.f;
  #pragma unroll
  for (int i = 0; i < 3; i++){
    u16x4 w = *(const u16x4*)(wr + i * 4);
    float4 b = *(const float4*)(br + i * 4);
    acc += bf2f(w[0]) * b.x + bf2f(w[1]) * b.y + bf2f(w[2]) * b.z + bf2f(w[3]) * b.w;
  }
  #pragma unroll
  for (int off = 32; off; off >>= 1) acc += __shfl_xor(acc, off);
  if (lane == 0){ bprime[n] = acc + bfc[n]; zb[n] = 0.f; }
}

// ---------------- spatial LN + vT zero-fill merged ----------------
__global__ __launch_bounds__(256)
void lnfz_k(const float* __restrict__ x, const u16* __restrict__ xt2,
            const float* __restrict__ gw, const float* __restrict__ bw,
            u16* __restrict__ out, u32* __restrict__ vzp, long nz){
  int b = blockIdx.x;
  if (b >= 3152){
    long i = (long)(b - 3152) * 256 + threadIdx.x;
    long stride = 2048L * 256;
    for (; i < nz; i += stride) vzp[i] = 0;
    return;
  }
  int lane = threadIdx.x & 63;
  int tok = b * 4 + (threadIdx.x >> 6);
  int s = tok / 197, j = tok - s * 197;
  int bb = s >> 4, tt = s & 15;
  float v[12]; float s1 = 0.f, s2 = 0.f;
  if (j == 0){
    const float* fsrc = x + (size_t)bb * 3137 * 768;
    #pragma unroll
    for (int i = 0; i < 3; i++){
      float4 f = *(const float4*)(fsrc + i * 256 + lane * 4);
      v[i*4+0] = f.x; v[i*4+1] = f.y; v[i*4+2] = f.z; v[i*4+3] = f.w;
    }
  } else {
    const u16* bsrc = xt2 + ((size_t)bb * 3136 + (size_t)(j - 1) * 16 + tt) * 768;
    #pragma unroll
    for (int i = 0; i < 3; i++){
      u16x4 p = *(const u16x4*)(bsrc + i * 256 + lane * 4);
      v[i*4+0] = bf2f(p[0]); v[i*4+1] = bf2f(p[1]); v[i*4+2] = bf2f(p[2]); v[i*4+3] = bf2f(p[3]);
    }
  }
  #pragma unroll
  for (int i = 0; i < 12; i++){ s1 += v[i]; s2 += v[i]*v[i]; }
  #pragma unroll
  for (int off = 32; off; off >>= 1){ s1 += __shfl_xor(s1, off); s2 += __shfl_xor(s2, off); }
  float mu = s1 * (1.f/768.f);
  float rstd = rsqrtf(s2 * (1.f/768.f) - mu*mu + 1e-5f);
  #pragma unroll
  for (int i = 0; i < 3; i++){
    int c = i * 256 + lane * 4;
    float4 g4 = *(const float4*)(gw + c);
    float4 b4 = *(const float4*)(bw + c);
    u16x4 pk;
    pk[0] = f2bf((v[i*4+0]-mu)*rstd*g4.x + b4.x);
    pk[1] = f2bf((v[i*4+1]-mu)*rstd*g4.y + b4.y);
    pk[2] = f2bf((v[i*4+2]-mu)*rstd*g4.z + b4.z);
    pk[3] = f2bf((v[i*4+3]-mu)*rstd*g4.w + b4.w);
    *(u16x4*)(out + (size_t)tok * 768 + c) = pk;
  }
}

// ---------------- final LN: reads bf16 xn ----------------
__global__ __launch_bounds__(256)
void ln2_k(const u16* __restrict__ xnb, const float* __restrict__ gw,
           const float* __restrict__ bw, u16* __restrict__ out){
  int lane = threadIdx.x & 63;
  int tok = blockIdx.x * 4 + (threadIdx.x >> 6);
  const u16* bsrc = xnb + (size_t)tok * 768;
  float v[12]; float s1 = 0.f, s2 = 0.f;
  #pragma unroll
  for (int i = 0; i < 3; i++){
    u16x4 p = *(const u16x4*)(bsrc + i * 256 + lane * 4);
    v[i*4+0] = bf2f(p[0]); v[i*4+1] = bf2f(p[1]); v[i*4+2] = bf2f(p[2]); v[i*4+3] = bf2f(p[3]);
  }
  #pragma unroll
  for (int i = 0; i < 12; i++){ s1 += v[i]; s2 += v[i]*v[i]; }
  #pragma unroll
  for (int off = 32; off; off >>= 1){ s1 += __shfl_xor(s1, off); s2 += __shfl_xor(s2, off); }
  float mu = s1 * (1.f/768.f);
  float rstd = rsqrtf(s2 * (1.f/768.f) - mu*mu + 1e-5f);
  #pragma unroll
  for (int i = 0; i < 3; i++){
    int c = i * 256 + lane * 4;
    float4 g4 = *(const float4*)(gw + c);
    float4 b4 = *(const float4*)(bw + c);
    u16x4 pk;
    pk[0] = f2bf((v[i*4+0]-mu)*rstd*g4.x + b4.x);
    pk[1] = f2bf((v[i*4+1]-mu)*rstd*g4.y + b4.y);
    pk[2] = f2bf((v[i*4+2]-mu)*rstd*g4.z + b4.z);
    pk[3] = f2bf((v[i*4+3]-mu)*rstd*g4.w + b4.w);
    *(u16x4*)(out + (size_t)tok * 768 + c) = pk;
  }
}

// ---------------- GEMM: C = Amap @ Bw^T(+bias), tri-tile, bf16 MFMA ----------------
// TILE=0: 128x128/256thr; TILE=1: 256x128/512thr; TILE=2: 64x128/256thr (small-K
// grid-starved only — R16/R18: loses at K=3072 and at non-starved grids).
// R18 lesson: BK=64 variant regresses (VGPR 88, LDS 64K -> occ 12.9%, m132 failure mode).
// MODE 0 bf16 | 1 blend RMW | 2 bf16 +f32 residual | 3 spatial scatter->bf16 xn (+cls)
// MODE 4 gelu | 5 f32 = val + bf16 xn | 8 temporal QKV | 9 spatial QKV (shifted vT)
template<int MODE, int TILE>
__global__ __launch_bounds__(TILE == 1 ? 512 : 256, TILE == 2 ? 5 : 4)
void gemm_k(const u16* __restrict__ A, const u16* __restrict__ Bw,
            const float* __restrict__ bias, void* out,
            const void* aux1, void* aux2, int nbx,
            int M, int K, int lda, int ldo,
            int aTs, int aTf, int at0, int oTs, int oTf, int ot0){
  constexpr int BM = (TILE == 1) ? 256 : (TILE == 0 ? 128 : 64);
  constexpr int THREADS = (TILE == 1) ? 512 : 256;
  constexpr int IM = (TILE == 2) ? 2 : 4;
  constexpr int WSPAN = IM * 16;
  constexpr bool A2 = (BM * 4 / THREADS) == 2;
  constexpr bool B2 = (512 / THREADS) == 2;
  __shared__ u16 lA[2][BM * 32];
  __shared__ u16 lB[2][128 * 32];
  const int tid = threadIdx.x;

  const int nwg = (int)gridDim.x;
  int id = (int)blockIdx.x;
  int qc = nwg >> 3, rc = nwg & 7;
  int xcd = id & 7, off = id >> 3;
  int wg = (xcd < rc ? xcd * (qc + 1) : rc * (qc + 1) + (xcd - rc) * qc) + off;
  int by = wg / nbx;
  int bx = wg - by * nbx;
  const int m0 = by * BM, n0 = bx * 128;

  const int lane = tid & 63, widx = tid >> 6;
  const int g = lane >> 4, r16 = lane & 15;
  const int wm = widx >> 1, wn = widx & 1;

  const u16* ga0; const u16* ga1 = nullptr; const u16* gb0; const u16* gb1 = nullptr;
  u32 loA0, loA1 = 0, loB0, loB1 = 0;
  {
    int li = tid;
    int ar = m0 + (li >> 2); if (ar > M - 1) ar = M - 1;
    ar = (ar / aTs) * aTf + at0 + (ar % aTs);
    ga0 = A + (size_t)ar * lda + (li & 3) * 8;
    loA0 = li * 8;
    if constexpr (A2){
      li = tid + THREADS;
      ar = m0 + (li >> 2); if (ar > M - 1) ar = M - 1;
      ar = (ar / aTs) * aTf + at0 + (ar % aTs);
      ga1 = A + (size_t)ar * lda + (li & 3) * 8;
      loA1 = li * 8;
    }
    gb0 = Bw + (size_t)(n0 + (tid >> 2)) * K + (tid & 3) * 8;
    loB0 = tid * 8;
    if constexpr (B2){
      int lj = tid + 256;
      gb1 = Bw + (size_t)(n0 + (lj >> 2)) * K + (lj & 3) * 8;
      loB1 = lj * 8;
    }
  }

  const f32x4 vz = {0.f, 0.f, 0.f, 0.f};
  f32x4 acc[IM][4];
  #pragma unroll
  for (int i = 0; i < IM; i++)
    #pragma unroll
    for (int j = 0; j < 4; j++) acc[i][j] = vz;

  const int kiter = K >> 5;

  gload16(ga0, &lA[0][loA0]);
  if constexpr (A2) gload16(ga1, &lA[0][loA1]);
  gload16(gb0, &lB[0][loB0]);
  if constexpr (B2) gload16(gb1, &lB[0][loB1]);
  ga0 += 32; gb0 += 32;
  if constexpr (A2) ga1 += 32;
  if constexpr (B2) gb1 += 32;
  __syncthreads();

  for (int kt = 0; kt < kiter; ++kt){
    const int cur = kt & 1;
    if (kt + 1 < kiter){
      const int nxt = cur ^ 1;
      gload16(ga0, &lA[nxt][loA0]);
      if constexpr (A2) gload16(ga1, &lA[nxt][loA1]);
      gload16(gb0, &lB[nxt][loB0]);
      if constexpr (B2) gload16(gb1, &lB[nxt][loB1]);
      ga0 += 32; gb0 += 32;
      if constexpr (A2) ga1 += 32;
      if constexpr (B2) gb1 += 32;
    }
    bf16x8 af[IM], bfr[4];
    #pragma unroll
    for (int i = 0; i < IM; i++)
      af[i]  = *(const bf16x8*)(&lA[cur][(wm * WSPAN + i * 16 + r16) * 32 + g * 8]);
    #pragma unroll
    for (int j = 0; j < 4; j++)
      bfr[j] = *(const bf16x8*)(&lB[cur][(wn * 64 + j * 16 + r16) * 32 + g * 8]);
    #pragma unroll
    for (int i = 0; i < IM; i++)
      #pragma unroll
      for (int j = 0; j < 4; j++)
        acc[i][j] = __builtin_amdgcn_mfma_f32_16x16x32_bf16(af[i], bfr[j], acc[i][j], 0, 0, 0);
    __syncthreads();
  }

  #pragma unroll
  for (int i = 0; i < IM; i++){
    const int lrow = wm * WSPAN + i * 16 + g * 4;
    #pragma unroll
    for (int j = 0; j < 4; j++){
      const int Cg = n0 + wn * 64 + j * 16 + r16;
      const float b0 = bias[Cg];
      float vv[4];
      #pragma unroll
      for (int r = 0; r < 4; r++) vv[r] = acc[i][j][r] + b0;

      if constexpr (MODE == 8){
        int mat = Cg / 768, c0 = Cg - mat * 768;
        if (mat < 2){
          #pragma unroll
          for (int r = 0; r < 4; r++){
            int R = m0 + lrow + r;
            if (R < M)
              ((u16*)out)[(size_t)mat * ot0 * 768 + (size_t)R * 768 + c0] = f2bf(vv[r]);
          }
        } else {
          int R0 = m0 + lrow;
          if (R0 < M){
            int seq_ = R0 / oTs, t0 = R0 - seq_ * oTs;
            u16x4 pk;
            #pragma unroll
            for (int r = 0; r < 4; r++) pk[r] = f2bf(vv[r]);
            *(u16x4*)((u16*)aux2 +
              ((size_t)(seq_ * 12 + (c0 >> 6)) * 64 + (c0 & 63)) * ldo + t0) = pk;
          }
        }
      } else if constexpr (MODE == 9){
        int mat = Cg / 768, c0 = Cg - mat * 768;
        if (mat < 2){
          #pragma unroll
          for (int r = 0; r < 4; r++){
            int R = m0 + lrow + r;
            if (R < M)
              ((u16*)out)[(size_t)mat * ot0 * 768 + (size_t)R * 768 + c0] = f2bf(vv[r]);
          }
        } else {
          int R0 = m0 + lrow;
          if (R0 < M){
            int s_ = R0 / 197, j0 = R0 - s_ * 197;
            if (j0 <= 193){
              u16x4 pk;
              #pragma unroll
              for (int r = 0; r < 4; r++) pk[r] = f2bf(vv[r]);
              *(u16x4*)((u16*)aux2 +
                ((size_t)(s_ * 12 + (c0 >> 6)) * 64 + (c0 & 63)) * 224 + j0 + (s_ & 3)) = pk;
            } else {
              #pragma unroll
              for (int r = 0; r < 4; r++){
                int R = R0 + r;
                if (R < M){
                  int s2 = R / 197, j2 = R - s2 * 197;
                  ((u16*)aux2)[((size_t)(s2 * 12 + (c0 >> 6)) * 64 + (c0 & 63)) * 224
                               + j2 + (s2 & 3)] = f2bf(vv[r]);
                }
              }
            }
          }
        }
      } else {
        #pragma unroll
        for (int r = 0; r < 4; r++){
          const int R = m0 + lrow + r;
          if (R >= M) continue;
          float val = vv[r];
          if constexpr (MODE == 0){
            ((u16*)out)[(size_t)R * ldo + Cg] = f2bf(val);
          } else if constexpr (MODE == 1){
            int Ro = (R / oTs) * oTf + ot0 + (R % oTs);
            u16* po = (u16*)out + (size_t)Ro * ldo + Cg;
            *po = f2bf(0.5f * val + 0.5f * bf2f(*po));
          } else if constexpr (MODE == 2){
            int b_ = R / 3136, m_ = R - b_ * 3136;
            ((u16*)out)[(size_t)R * 768 + Cg] =
                f2bf(val + ((const float*)aux1)[((size_t)b_ * 3137 + 1 + m_) * 768 + Cg]);
          } else if constexpr (MODE == 3){
            int s_ = R / 197, j_ = R - s_ * 197;
            if (j_ == 0){
              ((float*)aux2)[(size_t)s_ * 768 + Cg] = val;
            } else {
              int b_ = s_ >> 4, t_ = s_ & 15, m_ = (j_ - 1) * 16 + t_;
              ((u16*)out)[((size_t)b_ * 3137 + 1 + m_) * 768 + Cg] =
                  f2bf(val + bf2f(((const u16*)aux1)[((size_t)b_ * 3136 + m_) * 768 + Cg]));
            }
          } else if constexpr (MODE == 4){
            float c = val * (0.7978845608f + 0.0356774081f * val * val);
            float e2 = __expf(2.f * fabsf(c));
            float th = __builtin_copysignf(1.f - 2.f / (e2 + 1.f), c);
            ((u16*)out)[(size_t)R * ldo + Cg] = f2bf(0.5f * val * (1.f + th));
          } else if constexpr (MODE == 5){
            ((float*)out)[(size_t)R * 768 + Cg] =
                val + bf2f(((const u16*)aux1)[(size_t)R * 768 + Cg]);
          }
        }
      }
    }
  }
}

// ---------------- temporal attention via MFMA: one wave per (seq,head) ----------------
template<int TS, int TSPAD>
__global__ __launch_bounds__(256)
void tattn_k(const u16* __restrict__ q, const u16* __restrict__ k,
             const u16* __restrict__ vt, u16* __restrict__ o){
  const int lane = threadIdx.x & 63;
  const int g = lane >> 4, r16 = lane & 15;
  int p = blockIdx.x * 4 + (threadIdx.x >> 6);
  int seq = p / 12, h = p - seq * 12;

  int trow = (TS < 16 && r16 >= TS) ? TS - 1 : r16;
  size_t qko = (size_t)(seq * TS + trow) * 768 + h * 64 + g * 8;
  bf16x8 ak0 = *(const bf16x8*)(k + qko);
  bf16x8 ak1 = *(const bf16x8*)(k + qko + 32);
  bf16x8 bq0 = *(const bf16x8*)(q + qko);
  bf16x8 bq1 = *(const bf16x8*)(q + qko + 32);

  f32x4 s = {0.f, 0.f, 0.f, 0.f};
  s = __builtin_amdgcn_mfma_f32_16x16x32_bf16(ak0, bq0, s, 0, 0, 0);
  s = __builtin_amdgcn_mfma_f32_16x16x32_bf16(ak1, bq1, s, 0, 0, 0);

  const float C = 0.125f * 1.44269504089f;
  float pv[4]; float mx = -3e38f;
  #pragma unroll
  for (int r = 0; r < 4; r++){
    float x = (g * 4 + r < TS) ? s[r] : -3e38f;
    pv[r] = x; mx = fmaxf(mx, x);
  }
  mx = fmaxf(mx, __shfl_xor(mx, 16));
  mx = fmaxf(mx, __shfl_xor(mx, 32));
  float sum = 0.f;
  #pragma unroll
  for (int r = 0; r < 4; r++){ pv[r] = exp2f((pv[r] - mx) * C); sum += pv[r]; }
  sum += __shfl_xor(sum, 16);
  sum += __shfl_xor(sum, 32);
  float inv = 1.f / sum;
  #pragma unroll
  for (int r = 0; r < 4; r++) pv[r] *= inv;

  u32 w0 = (u32)f2bf(pv[0]) | ((u32)f2bf(pv[1]) << 16);
  u32 w1 = (u32)f2bf(pv[2]) | ((u32)f2bf(pv[3]) << 16);
  int a0 = ((g * 2) * 16 + r16) * 4;
  int a1 = ((g * 2 + 1) * 16 + r16) * 4;
  u32 msk = (g < 2) ? 0xFFFFFFFFu : 0u;
  union { u32 w[4]; bf16x8 v; } pa;
  pa.w[0] = msk & (u32)__builtin_amdgcn_ds_bpermute(a0, (int)w0);
  pa.w[1] = msk & (u32)__builtin_amdgcn_ds_bpermute(a0, (int)w1);
  pa.w[2] = msk & (u32)__builtin_amdgcn_ds_bpermute(a1, (int)w0);
  pa.w[3] = msk & (u32)__builtin_amdgcn_ds_bpermute(a1, (int)w1);

  const u16* vb = vt + ((size_t)(seq * 12 + h) * 64) * TSPAD;
  const f32x4 vz = {0.f, 0.f, 0.f, 0.f};
  f32x4 oc[4];
  #pragma unroll
  for (int dt = 0; dt < 4; ++dt){
    bf16x8 bv = *(const bf16x8*)(vb + (size_t)(dt * 16 + r16) * TSPAD + g * 8);
    oc[dt] = __builtin_amdgcn_mfma_f32_16x16x32_bf16(pa.v, bv, vz, 0, 0, 0);
  }
  #pragma unroll
  for (int rr = 0; rr < 4; ++rr){
    int qr = g * 4 + rr;
    if (qr < TS){
      size_t ob = (size_t)(seq * TS + qr) * 768 + h * 64 + r16;
      #pragma unroll
      for (int dt = 0; dt < 4; ++dt)
        o[ob + dt * 16] = f2bf(oc[dt][rr]);
    }
  }
}

// ---------------- spatial attention: 4 waves/block ----------------
__global__ __launch_bounds__(256)
void sattn_k(const u16* __restrict__ qs, const u16* __restrict__ ks,
             const u16* __restrict__ vt, u16* __restrict__ o){
  __shared__ u16 PlAll[4][16 * 224];
  const int wid = threadIdx.x >> 6;
  u16* Pl = PlAll[wid];
  const int lane = threadIdx.x & 63;
  const int g = lane >> 4, r16 = lane & 15;
  int gi = blockIdx.x * 4 + wid;
  int chunk = gi % 13; int sh_ = gi / 13;
  int h = sh_ % 12, s = sh_ / 12;
  const int shft = s & 3;
  const float sc_l2e = 0.125f * 1.44269504089f;

  #pragma unroll
  for (int i = 0; i < 4; i++){
    Pl[(i * 4 + g) * 224 + 208 + r16] = 0;
    if (r16 < 4) Pl[(i * 4 + g) * 224 + r16] = 0;
  }

  int q0 = chunk * 16;
  int qrow = q0 + r16; if (qrow > 196) qrow = 196;
  const u16* qp = qs + ((size_t)(s * 197 + qrow)) * 768 + h * 64 + g * 8;
  bf16x8 aq0 = *(const bf16x8*)qp;
  bf16x8 aq1 = *(const bf16x8*)(qp + 32);

  f32x4 scv[13];
  #pragma unroll
  for (int jt = 0; jt < 13; ++jt){
    int krow = jt * 16 + r16; if (krow > 196) krow = 196;
    const u16* kp = ks + ((size_t)(s * 197 + krow)) * 768 + h * 64 + g * 8;
    bf16x8 b0 = *(const bf16x8*)kp;
    bf16x8 b1 = *(const bf16x8*)(kp + 32);
    f32x4 z = {0.f, 0.f, 0.f, 0.f};
    z = __builtin_amdgcn_mfma_f32_16x16x32_bf16(aq0, b0, z, 0, 0, 0);
    z = __builtin_amdgcn_mfma_f32_16x16x32_bf16(aq1, b1, z, 0, 0, 0);
    scv[jt] = z;
  }
  float mrow[4] = {-3e38f, -3e38f, -3e38f, -3e38f};
  #pragma unroll
  for (int jt = 0; jt < 13; ++jt)
    #pragma unroll
    for (int r = 0; r < 4; r++){
      float x = (jt * 16 + r16 < 197) ? scv[jt][r] : -3e38f;
      scv[jt][r] = x;
      mrow[r] = fmaxf(mrow[r], x);
    }
  #pragma unroll
  for (int off = 1; off < 16; off <<= 1)
    #pragma unroll
    for (int r = 0; r < 4; r++) mrow[r] = fmaxf(mrow[r], __shfl_xor(mrow[r], off));
  float srow[4] = {0.f, 0.f, 0.f, 0.f};
  #pragma unroll
  for (int jt = 0; jt < 13; ++jt)
    #pragma unroll
    for (int r = 0; r < 4; r++){
      float e = exp2f((scv[jt][r] - mrow[r]) * sc_l2e);
      scv[jt][r] = e;
      srow[r] += e;
    }
  #pragma unroll
  for (int off = 1; off < 16; off <<= 1)
    #pragma unroll
    for (int r = 0; r < 4; r++) srow[r] += __shfl_xor(srow[r], off);
  float inv[4];
  #pragma unroll
  for (int r = 0; r < 4; r++) inv[r] = 1.f / srow[r];
  #pragma unroll
  for (int jt = 0; jt < 13; ++jt)
    #pragma unroll
    for (int r = 0; r < 4; r++)
      Pl[(g * 4 + r) * 224 + jt * 16 + r16 + shft] = f2bf(scv[jt][r] * inv[r]);
  __syncthreads();
  const u16* vbase = vt + ((size_t)(s * 12 + h) * 64) * 224;
  f32x4 oc[4]; const f32x4 vz = {0.f,0.f,0.f,0.f};
  #pragma unroll
  for (int dt = 0; dt < 4; dt++) oc[dt] = vz;
  #pragma unroll
  for (int ks2 = 0; ks2 < 7; ++ks2){
    bf16x8 ap = *(const bf16x8*)(Pl + r16 * 224 + ks2 * 32 + g * 8);
    #pragma unroll
    for (int dt = 0; dt < 4; ++dt){
      const u16* vp = vbase + ((size_t)(dt * 16 + r16)) * 224 + ks2 * 32 + g * 8;
      bf16x8 bv = *(const bf16x8*)vp;
      oc[dt] = __builtin_amdgcn_mfma_f32_16x16x32_bf16(ap, bv, oc[dt], 0, 0, 0);
    }
  }
  #pragma unroll
  for (int dt = 0; dt < 4; ++dt)
    #pragma unroll
    for (int r = 0; r < 4; r++){
      int qr2 = q0 + g * 4 + r;
      if (qr2 < 197)
        o[((size_t)(s * 197 + qr2)) * 768 + h * 64 + dt * 16 + r16] = f2bf(oc[dt][r]);
    }
}

// ---------------- cls row: xn[b,0] = bf16(x[b,0] + mean_t clsbuf[b*16+t]) --------------
__global__ __launch_bounds__(256)
void clsfin_k(const float* __restrict__ x, const float* __restrict__ cb, u16* __restrict__ xn){
  int b = blockIdx.x;
  int c = blockIdx.y * 256 + threadIdx.x;
  float s = 0.f;
  #pragma unroll
  for (int t = 0; t < 16; t++) s += cb[((size_t)(b * 16 + t)) * 768 + c];
  xn[(size_t)b * 3137 * 768 + c] = f2bf(x[(size_t)b * 3137 * 768 + c] + s * (1.f / 16.f));
}

// ======================================================================================
extern "C" void kernel_launch(void* const* d_in, const int* in_sizes, int n_in,
                              void* d_out, int out_size, void* d_ws, size_t ws_size,
                              hipStream_t stream){
  (void)in_sizes; (void)n_in; (void)out_size;
  const float* x    = (const float*)d_in[0];
  const float* ln1g = (const float*)d_in[1];
  const float* ln1b = (const float*)d_in[2];
  const float* tlng = (const float*)d_in[3];
  const float* tlnb = (const float*)d_in[4];
  const float* ln2g = (const float*)d_in[5];
  const float* ln2b = (const float*)d_in[6];
  const float* Ws   = (const float*)d_in[7];
  const float* bs   = (const float*)d_in[8];
  const float* Wt   = (const float*)d_in[9];
  const float* bt   = (const float*)d_in[10];
  const float* Wtp  = (const float*)d_in[11];
  const float* btp  = (const float*)d_in[12];
  const float* Wfc  = (const float*)d_in[13];
  const float* bfc  = (const float*)d_in[14];
  const float* W1   = (const float*)d_in[15];
  const float* b1   = (const float*)d_in[16];
  const float* W2   = (const float*)d_in[17];
  const float* b2   = (const float*)d_in[18];
  float* out = (float*)d_out;

  constexpr size_t MiB = 1048576;
  constexpr size_t C2  = 589824;
  constexpr size_t W_BYTES = (17 * C2 + 2 * 2359296) * 2;  // 29,491,200
  constexpr size_t NEED = W_BYTES + 143 * MiB;
  if (ws_size < NEED) return;

  char* wsb  = (char*)d_ws;
  u16*  wbuf = (u16*)wsb;
  u16*  W1T  = wbuf + 17 * C2;
  u16*  W2T  = W1T + (size_t)3072 * 768;
  char* A0   = wsb + W_BYTES;

  u16*  ht  = (u16*)(A0 + 0   * MiB);
  u16*  qk  = (u16*)(A0 + 20  * MiB);
  u16*  vtb = (u16*)(A0 + 58  * MiB);
  u16*  o16 = (u16*)(A0 + 86  * MiB);
  u16*  o8  = (u16*)(A0 + 105 * MiB);
  u16*  o4  = (u16*)(A0 + 115 * MiB);
  u16*  xt2 = (u16*)(A0 + 105 * MiB);
  u16*  xnb = (u16*)(A0 + 20 * MiB);
  u16*  wtp2b = (u16*)(A0 + 132 * MiB);
  u16*  WpT   = (u16*)(A0 + 134 * MiB);
  float* bprime = (float*)(A0 + 136 * MiB);
  float* zb     = bprime + 1024;
  float* clsb = (float*)(A0 + 142 * MiB);
  u16*  hs  = ht;  u16* osb = ht; u16* h2 = ht;
  u16*  a1  = (u16*)(A0 + 58 * MiB);

  // -- fused weight prep + temporal LN, bias fold, W' GEMM
  wprep_k<<<18112, 256, 0, stream>>>(Ws, Wt, Wtp, Wfc, wbuf, W1, W1T, W2, W2T,
                                     wtp2b, x, tlng, tlnb, ht);
  bprep_k<<<192, 256, 0, stream>>>(btp + 1536, wbuf + 16*C2, bfc, bprime, zb);
  gemm_k<0,2><<<12*6, 256, 0, stream>>>(wbuf + 16*C2, wtp2b, zb, WpT, nullptr, nullptr, 6, 768, 768, 768, 768, 1,1,0, 1,1,0);

  // -- scale 16: fused QKV + attn  [BIG tile]
  gemm_k<8,1><<<49*18, 512, 0, stream>>>(ht, wbuf + 10*C2, bt + 6*768, qk, nullptr, vtb, 18, 12544, 768, 768, 24, 1,1,0, 16,1,12544);
  tattn_k<16,24><<<2352, 256, 0, stream>>>(qk, qk + (size_t)12544*768, vtb, o16);

  // -- scale 8  [128 tile]
  gemm_k<8,0><<<49*18, 256, 0, stream>>>(ht, wbuf +  7*C2, bt + 3*768, qk, nullptr, vtb, 18, 6272, 768, 768, 16, 8,16,8, 8,1,6272);
  tattn_k< 8,16><<<2352, 256, 0, stream>>>(qk, qk + (size_t)6272*768, vtb, o8);

  // -- scale 4  [128 tile]
  gemm_k<8,0><<<25*18, 256, 0, stream>>>(ht, wbuf +  4*C2, bt + 0*768, qk, nullptr, vtb, 18, 3136, 768, 768, 16, 4,16,12, 4,1,3136);
  tattn_k< 4,16><<<2352, 256, 0, stream>>>(qk, qk + (size_t)3136*768, vtb, o4);

  // -- blend chain + collapsed xt2  [thin 64 tile: small-K grid-starved]
  gemm_k<1,2><<<49*6, 256, 0, stream>>>(o4,  wbuf + 13*C2, btp + 0,   o8,  nullptr, nullptr, 6, 3136, 768, 768, 768, 1,1,0, 4,8,4);
  gemm_k<1,2><<<98*6, 256, 0, stream>>>(o8,  wbuf + 14*C2, btp + 768, o16, nullptr, nullptr, 6, 6272, 768, 768, 768, 1,1,0, 8,16,8);
  gemm_k<2,2><<<196*6, 256, 0, stream>>>(o16, WpT,         bprime,    xt2, x, nullptr,       6, 12544, 768, 768, 768, 1,1,0, 1,1,0);

  // -- spatial LN + vT zero-fill, fused QKV  [BIG tile]
  lnfz_k<<<5200, 256, 0, stream>>>(x, xt2, ln1g, ln1b, hs, (u32*)vtb, 5505024);
  gemm_k<9,1><<<50*18, 512, 0, stream>>>(hs, wbuf + 0*C2, bs + 0, qk, nullptr, vtb, 18, 12608, 768, 768, 224, 1,1,0, 1,1,12608);

  // -- spatial attention
  sattn_k<<<2496, 256, 0, stream>>>(qk, qk + (size_t)12608*768, vtb, osb);

  // -- spatial proj + residual scatter  [thin tile, K=768]
  gemm_k<3,2><<<197*6, 256, 0, stream>>>(osb, wbuf + 3*C2, bs + 2304, xnb, xt2, clsb, 6, 12608, 768, 768, 768, 1,1,0, 1,1,0);
  clsfin_k<<<dim3(4, 3), 256, 0, stream>>>(x, clsb, xnb);

  // -- final LN + MLP  [up: BIG; down: 128 tile (K=3072)]
  ln2_k<<<3137, 256, 0, stream>>>(xnb, ln2g, ln2b, h2);
  gemm_k<4,1><<<50*24, 512, 0, stream>>>(h2, W1T, b1, a1,  nullptr, nullptr, 24, 12548, 768, 768, 3072, 1,1,0, 1,1,0);
  gemm_k<5,0><<<99*6, 256, 0, stream>>>(a1, W2T, b2, out, xnb, nullptr,      6, 12548, 3072, 3072, 768, 1,1,0, 1,1,0);
}

// Round 20
// 670.124 us; speedup vs baseline: 1.1200x; 1.0130x over previous
//
#include <hip/hip_runtime.h>

typedef unsigned short u16;
typedef unsigned int   u32;
typedef __attribute__((ext_vector_type(8))) __bf16 bf16x8;
typedef __attribute__((ext_vector_type(4))) float  f32x4;
typedef __attribute__((ext_vector_type(4))) u16    u16x4;

#define DEV __device__ __forceinline__

DEV float bf2f(u16 u){ union { u32 i; float f; } x; x.i = ((u32)u) << 16; return x.f; }
DEV u16 f2bf(float f){ union { float f; u32 i; } x; x.f = f;
  u32 r = x.i + 0x7fffu + ((x.i >> 16) & 1u); return (u16)(r >> 16); }

DEV void gload16(const void* g, void* l){
  __builtin_amdgcn_global_load_lds((const __attribute__((address_space(1))) void*)g,
                                   (__attribute__((address_space(3))) void*)l, 16, 0, 0);
}

// ---------------- fused weight prep + temporal LN (independent parts, one launch) ------
__global__ __launch_bounds__(256)
void wprep_k(const float* __restrict__ Ws, const float* __restrict__ Wt,
             const float* __restrict__ Wtp, const float* __restrict__ Wfc,
             u16* __restrict__ wbuf,
             const float* __restrict__ W1, u16* __restrict__ W1T,
             const float* __restrict__ W2, u16* __restrict__ W2T,
             u16* __restrict__ wtp2b,
             const float* __restrict__ x, const float* __restrict__ tlng,
             const float* __restrict__ tlnb, u16* __restrict__ ht){
  __shared__ float t[32][33];
  const int b = blockIdx.x, tid = threadIdx.x;
  if (b < 9792){
    int z = b / 576, r2 = b - z * 576;
    int c0 = (r2 % 24) * 32, r0 = (r2 / 24) * 32;
    const float* src = (z < 4)  ? Ws  + (size_t)z * 589824
                     : (z < 13) ? Wt  + (size_t)(z-4) * 589824
                     : (z < 16) ? Wtp + (size_t)(z-13) * 589824
                     : Wfc;
    u16* d = wbuf + (size_t)z * 589824;
    int tx = tid & 31, ty = tid >> 5;
    #pragma unroll
    for (int i = 0; i < 4; i++)
      t[ty + i*8][tx] = src[(size_t)(r0 + ty + i*8) * 768 + c0 + tx];
    __syncthreads();
    #pragma unroll
    for (int i = 0; i < 4; i++)
      d[(size_t)(c0 + ty + i*8) * 768 + r0 + tx] = f2bf(t[tx][ty + i*8]);
  } else if (b < 14400){
    const float* src; u16* dst; int R, C, bx, by;
    if (b < 12096){ int r = b - 9792;  src = W1; dst = W1T; R = 768;  C = 3072; bx = r % 96; by = r / 96; }
    else          { int r = b - 12096; src = W2; dst = W2T; R = 3072; C = 768;  bx = r % 24; by = r / 24; }
    int c0 = bx * 32, r0 = by * 32;
    int tx = tid & 31, ty = tid >> 5;
    #pragma unroll
    for (int i = 0; i < 4; i++)
      t[ty + i*8][tx] = src[(size_t)(r0 + ty + i*8) * C + c0 + tx];
    __syncthreads();
    #pragma unroll
    for (int i = 0; i < 4; i++)
      dst[(size_t)(c0 + ty + i*8) * R + r0 + tx] = f2bf(t[tx][ty + i*8]);
  } else if (b < 14976){
    int i = ((b - 14400) * 256 + tid) * 4;
    float4 f = *(const float4*)(Wtp + 2 * 589824 + i);
    u16x4 p; p[0] = f2bf(f.x); p[1] = f2bf(f.y); p[2] = f2bf(f.z); p[3] = f2bf(f.w);
    *(u16x4*)(wtp2b + i) = p;
  } else {
    int lane = tid & 63;
    int tok = (b - 14976) * 4 + (tid >> 6);
    int bb = tok / 3136, m = tok - bb * 3136;
    const float* fsrc = x + ((size_t)bb * 3137 + 1 + m) * 768;
    float v[12]; float s1 = 0.f, s2 = 0.f;
    #pragma unroll
    for (int i = 0; i < 3; i++){
      float4 f = *(const float4*)(fsrc + i * 256 + lane * 4);
      v[i*4+0] = f.x; v[i*4+1] = f.y; v[i*4+2] = f.z; v[i*4+3] = f.w;
    }
    #pragma unroll
    for (int i = 0; i < 12; i++){ s1 += v[i]; s2 += v[i]*v[i]; }
    #pragma unroll
    for (int off = 32; off; off >>= 1){ s1 += __shfl_xor(s1, off); s2 += __shfl_xor(s2, off); }
    float mu = s1 * (1.f/768.f);
    float rstd = rsqrtf(s2 * (1.f/768.f) - mu*mu + 1e-5f);
    #pragma unroll
    for (int i = 0; i < 3; i++){
      int c = i * 256 + lane * 4;
      float4 g4 = *(const float4*)(tlng + c);
      float4 b4 = *(const float4*)(tlnb + c);
      u16x4 pk;
      pk[0] = f2bf((v[i*4+0]-mu)*rstd*g4.x + b4.x);
      pk[1] = f2bf((v[i*4+1]-mu)*rstd*g4.y + b4.y);
      pk[2] = f2bf((v[i*4+2]-mu)*rstd*g4.z + b4.z);
      pk[3] = f2bf((v[i*4+3]-mu)*rstd*g4.w + b4.w);
      *(u16x4*)(ht + (size_t)tok * 768 + c) = pk;
    }
  }
}

// ---------------- bias fold, one WAVE per n ----------------
__global__ __launch_bounds__(256)
void bprep_k(const float* __restrict__ btp2, const u16* __restrict__ WfcT,
             const float* __restrict__ bfc, float* __restrict__ bprime,
             float* __restrict__ zb){
  int lane = threadIdx.x & 63;
  int n = blockIdx.x * 4 + (threadIdx.x >> 6);
  const u16* wr = WfcT + (size_t)n * 768 + lane * 12;
  const float* br = btp2 + lane * 12;
  float acc = 0.f;
  #pragma unroll
  for (int i = 0; i < 3; i++){
    u16x4 w = *(const u16x4*)(wr + i * 4);
    float4 b = *(const float4*)(br + i * 4);
    acc += bf2f(w[0]) * b.x + bf2f(w[1]) * b.y + bf2f(w[2]) * b.z + bf2f(w[3]) * b.w;
  }
  #pragma unroll
  for (int off = 32; off; off >>= 1) acc += __shfl_xor(acc, off);
  if (lane == 0){ bprime[n] = acc + bfc[n]; zb[n] = 0.f; }
}

// ---------------- spatial LN + vT zero-fill merged ----------------
__global__ __launch_bounds__(256)
void lnfz_k(const float* __restrict__ x, const u16* __restrict__ xt2,
            const float* __restrict__ gw, const float* __restrict__ bw,
            u16* __restrict__ out, u32* __restrict__ vzp, long nz){
  int b = blockIdx.x;
  if (b >= 3152){
    long i = (long)(b - 3152) * 256 + threadIdx.x;
    long stride = 2048L * 256;
    for (; i < nz; i += stride) vzp[i] = 0;
    return;
  }
  int lane = threadIdx.x & 63;
  int tok = b * 4 + (threadIdx.x >> 6);
  int s = tok / 197, j = tok - s * 197;
  int bb = s >> 4, tt = s & 15;
  float v[12]; float s1 = 0.f, s2 = 0.f;
  if (j == 0){
    const float* fsrc = x + (size_t)bb * 3137 * 768;
    #pragma unroll
    for (int i = 0; i < 3; i++){
      float4 f = *(const float4*)(fsrc + i * 256 + lane * 4);
      v[i*4+0] = f.x; v[i*4+1] = f.y; v[i*4+2] = f.z; v[i*4+3] = f.w;
    }
  } else {
    const u16* bsrc = xt2 + ((size_t)bb * 3136 + (size_t)(j - 1) * 16 + tt) * 768;
    #pragma unroll
    for (int i = 0; i < 3; i++){
      u16x4 p = *(const u16x4*)(bsrc + i * 256 + lane * 4);
      v[i*4+0] = bf2f(p[0]); v[i*4+1] = bf2f(p[1]); v[i*4+2] = bf2f(p[2]); v[i*4+3] = bf2f(p[3]);
    }
  }
  #pragma unroll
  for (int i = 0; i < 12; i++){ s1 += v[i]; s2 += v[i]*v[i]; }
  #pragma unroll
  for (int off = 32; off; off >>= 1){ s1 += __shfl_xor(s1, off); s2 += __shfl_xor(s2, off); }
  float mu = s1 * (1.f/768.f);
  float rstd = rsqrtf(s2 * (1.f/768.f) - mu*mu + 1e-5f);
  #pragma unroll
  for (int i = 0; i < 3; i++){
    int c = i * 256 + lane * 4;
    float4 g4 = *(const float4*)(gw + c);
    float4 b4 = *(const float4*)(bw + c);
    u16x4 pk;
    pk[0] = f2bf((v[i*4+0]-mu)*rstd*g4.x + b4.x);
    pk[1] = f2bf((v[i*4+1]-mu)*rstd*g4.y + b4.y);
    pk[2] = f2bf((v[i*4+2]-mu)*rstd*g4.z + b4.z);
    pk[3] = f2bf((v[i*4+3]-mu)*rstd*g4.w + b4.w);
    *(u16x4*)(out + (size_t)tok * 768 + c) = pk;
  }
}

// ---------------- final LN (+ inlined cls-row finish for tok = b*3137) ----------------
// cls tokens: xn = x[b,0] + mean_t clsb[b*16+t]; write bf16 xnb (read later by MODE 5)
// and LN from the f32 values. Non-cls: read bf16 xnb as before.
__global__ __launch_bounds__(256)
void ln2_k(u16* __restrict__ xnb, const float* __restrict__ gw,
           const float* __restrict__ bw, u16* __restrict__ out,
           const float* __restrict__ x, const float* __restrict__ cb){
  int lane = threadIdx.x & 63;
  int tok = blockIdx.x * 4 + (threadIdx.x >> 6);
  int b_ = tok / 3137;
  bool iscls = (tok - b_ * 3137) == 0;
  float v[12]; float s1 = 0.f, s2 = 0.f;
  if (iscls){
    const float* fx = x + (size_t)b_ * 3137 * 768;
    const float* fc = cb + (size_t)b_ * 16 * 768;
    #pragma unroll
    for (int i = 0; i < 3; i++){
      int c = i * 256 + lane * 4;
      float4 xv = *(const float4*)(fx + c);
      float sx = 0.f, sy = 0.f, sz = 0.f, sw = 0.f;
      for (int t = 0; t < 16; t++){
        float4 cv = *(const float4*)(fc + (size_t)t * 768 + c);
        sx += cv.x; sy += cv.y; sz += cv.z; sw += cv.w;
      }
      v[i*4+0] = xv.x + sx * 0.0625f;
      v[i*4+1] = xv.y + sy * 0.0625f;
      v[i*4+2] = xv.z + sz * 0.0625f;
      v[i*4+3] = xv.w + sw * 0.0625f;
      u16x4 pk;
      pk[0] = f2bf(v[i*4+0]); pk[1] = f2bf(v[i*4+1]);
      pk[2] = f2bf(v[i*4+2]); pk[3] = f2bf(v[i*4+3]);
      *(u16x4*)(xnb + (size_t)tok * 768 + c) = pk;
    }
  } else {
    const u16* bsrc = xnb + (size_t)tok * 768;
    #pragma unroll
    for (int i = 0; i < 3; i++){
      u16x4 p = *(const u16x4*)(bsrc + i * 256 + lane * 4);
      v[i*4+0] = bf2f(p[0]); v[i*4+1] = bf2f(p[1]); v[i*4+2] = bf2f(p[2]); v[i*4+3] = bf2f(p[3]);
    }
  }
  #pragma unroll
  for (int i = 0; i < 12; i++){ s1 += v[i]; s2 += v[i]*v[i]; }
  #pragma unroll
  for (int off = 32; off; off >>= 1){ s1 += __shfl_xor(s1, off); s2 += __shfl_xor(s2, off); }
  float mu = s1 * (1.f/768.f);
  float rstd = rsqrtf(s2 * (1.f/768.f) - mu*mu + 1e-5f);
  #pragma unroll
  for (int i = 0; i < 3; i++){
    int c = i * 256 + lane * 4;
    float4 g4 = *(const float4*)(gw + c);
    float4 b4 = *(const float4*)(bw + c);
    u16x4 pk;
    pk[0] = f2bf((v[i*4+0]-mu)*rstd*g4.x + b4.x);
    pk[1] = f2bf((v[i*4+1]-mu)*rstd*g4.y + b4.y);
    pk[2] = f2bf((v[i*4+2]-mu)*rstd*g4.z + b4.z);
    pk[3] = f2bf((v[i*4+3]-mu)*rstd*g4.w + b4.w);
    *(u16x4*)(out + (size_t)tok * 768 + c) = pk;
  }
}

// ---------------- GEMM: C = Amap @ Bw^T(+bias), tri-tile, bf16 MFMA ----------------
// TILE=0: 128x128/256thr; TILE=1: 256x128/512thr; TILE=2: 64x128/256thr (small-K
// grid-starved only). R18: BK=64 regresses (occupancy collapse, m132 failure mode).
// MODE 0 bf16 | 1 blend RMW | 2 bf16 +f32 residual | 3 spatial scatter->bf16 xn (+cls)
// MODE 4 gelu (sigmoid form, R20) | 5 f32 = val + bf16 xn | 8 temporal QKV | 9 spatial QKV
template<int MODE, int TILE>
__global__ __launch_bounds__(TILE == 1 ? 512 : 256, TILE == 2 ? 5 : 4)
void gemm_k(const u16* __restrict__ A, const u16* __restrict__ Bw,
            const float* __restrict__ bias, void* out,
            const void* aux1, void* aux2, int nbx,
            int M, int K, int lda, int ldo,
            int aTs, int aTf, int at0, int oTs, int oTf, int ot0){
  constexpr int BM = (TILE == 1) ? 256 : (TILE == 0 ? 128 : 64);
  constexpr int THREADS = (TILE == 1) ? 512 : 256;
  constexpr int IM = (TILE == 2) ? 2 : 4;
  constexpr int WSPAN = IM * 16;
  constexpr bool A2 = (BM * 4 / THREADS) == 2;
  constexpr bool B2 = (512 / THREADS) == 2;
  __shared__ u16 lA[2][BM * 32];
  __shared__ u16 lB[2][128 * 32];
  const int tid = threadIdx.x;

  const int nwg = (int)gridDim.x;
  int id = (int)blockIdx.x;
  int qc = nwg >> 3, rc = nwg & 7;
  int xcd = id & 7, off = id >> 3;
  int wg = (xcd < rc ? xcd * (qc + 1) : rc * (qc + 1) + (xcd - rc) * qc) + off;
  int by = wg / nbx;
  int bx = wg - by * nbx;
  const int m0 = by * BM, n0 = bx * 128;

  const int lane = tid & 63, widx = tid >> 6;
  const int g = lane >> 4, r16 = lane & 15;
  const int wm = widx >> 1, wn = widx & 1;

  const u16* ga0; const u16* ga1 = nullptr; const u16* gb0; const u16* gb1 = nullptr;
  u32 loA0, loA1 = 0, loB0, loB1 = 0;
  {
    int li = tid;
    int ar = m0 + (li >> 2); if (ar > M - 1) ar = M - 1;
    ar = (ar / aTs) * aTf + at0 + (ar % aTs);
    ga0 = A + (size_t)ar * lda + (li & 3) * 8;
    loA0 = li * 8;
    if constexpr (A2){
      li = tid + THREADS;
      ar = m0 + (li >> 2); if (ar > M - 1) ar = M - 1;
      ar = (ar / aTs) * aTf + at0 + (ar % aTs);
      ga1 = A + (size_t)ar * lda + (li & 3) * 8;
      loA1 = li * 8;
    }
    gb0 = Bw + (size_t)(n0 + (tid >> 2)) * K + (tid & 3) * 8;
    loB0 = tid * 8;
    if constexpr (B2){
      int lj = tid + 256;
      gb1 = Bw + (size_t)(n0 + (lj >> 2)) * K + (lj & 3) * 8;
      loB1 = lj * 8;
    }
  }

  const f32x4 vz = {0.f, 0.f, 0.f, 0.f};
  f32x4 acc[IM][4];
  #pragma unroll
  for (int i = 0; i < IM; i++)
    #pragma unroll
    for (int j = 0; j < 4; j++) acc[i][j] = vz;

  const int kiter = K >> 5;

  gload16(ga0, &lA[0][loA0]);
  if constexpr (A2) gload16(ga1, &lA[0][loA1]);
  gload16(gb0, &lB[0][loB0]);
  if constexpr (B2) gload16(gb1, &lB[0][loB1]);
  ga0 += 32; gb0 += 32;
  if constexpr (A2) ga1 += 32;
  if constexpr (B2) gb1 += 32;
  __syncthreads();

  for (int kt = 0; kt < kiter; ++kt){
    const int cur = kt & 1;
    if (kt + 1 < kiter){
      const int nxt = cur ^ 1;
      gload16(ga0, &lA[nxt][loA0]);
      if constexpr (A2) gload16(ga1, &lA[nxt][loA1]);
      gload16(gb0, &lB[nxt][loB0]);
      if constexpr (B2) gload16(gb1, &lB[nxt][loB1]);
      ga0 += 32; gb0 += 32;
      if constexpr (A2) ga1 += 32;
      if constexpr (B2) gb1 += 32;
    }
    bf16x8 af[IM], bfr[4];
    #pragma unroll
    for (int i = 0; i < IM; i++)
      af[i]  = *(const bf16x8*)(&lA[cur][(wm * WSPAN + i * 16 + r16) * 32 + g * 8]);
    #pragma unroll
    for (int j = 0; j < 4; j++)
      bfr[j] = *(const bf16x8*)(&lB[cur][(wn * 64 + j * 16 + r16) * 32 + g * 8]);
    #pragma unroll
    for (int i = 0; i < IM; i++)
      #pragma unroll
      for (int j = 0; j < 4; j++)
        acc[i][j] = __builtin_amdgcn_mfma_f32_16x16x32_bf16(af[i], bfr[j], acc[i][j], 0, 0, 0);
    __syncthreads();
  }

  #pragma unroll
  for (int i = 0; i < IM; i++){
    const int lrow = wm * WSPAN + i * 16 + g * 4;
    #pragma unroll
    for (int j = 0; j < 4; j++){
      const int Cg = n0 + wn * 64 + j * 16 + r16;
      const float b0 = bias[Cg];
      float vv[4];
      #pragma unroll
      for (int r = 0; r < 4; r++) vv[r] = acc[i][j][r] + b0;

      if constexpr (MODE == 8){
        int mat = Cg / 768, c0 = Cg - mat * 768;
        if (mat < 2){
          #pragma unroll
          for (int r = 0; r < 4; r++){
            int R = m0 + lrow + r;
            if (R < M)
              ((u16*)out)[(size_t)mat * ot0 * 768 + (size_t)R * 768 + c0] = f2bf(vv[r]);
          }
        } else {
          int R0 = m0 + lrow;
          if (R0 < M){
            int seq_ = R0 / oTs, t0 = R0 - seq_ * oTs;
            u16x4 pk;
            #pragma unroll
            for (int r = 0; r < 4; r++) pk[r] = f2bf(vv[r]);
            *(u16x4*)((u16*)aux2 +
              ((size_t)(seq_ * 12 + (c0 >> 6)) * 64 + (c0 & 63)) * ldo + t0) = pk;
          }
        }
      } else if constexpr (MODE == 9){
        int mat = Cg / 768, c0 = Cg - mat * 768;
        if (mat < 2){
          #pragma unroll
          for (int r = 0; r < 4; r++){
            int R = m0 + lrow + r;
            if (R < M)
              ((u16*)out)[(size_t)mat * ot0 * 768 + (size_t)R * 768 + c0] = f2bf(vv[r]);
          }
        } else {
          int R0 = m0 + lrow;
          if (R0 < M){
            int s_ = R0 / 197, j0 = R0 - s_ * 197;
            if (j0 <= 193){
              u16x4 pk;
              #pragma unroll
              for (int r = 0; r < 4; r++) pk[r] = f2bf(vv[r]);
              *(u16x4*)((u16*)aux2 +
                ((size_t)(s_ * 12 + (c0 >> 6)) * 64 + (c0 & 63)) * 224 + j0 + (s_ & 3)) = pk;
            } else {
              #pragma unroll
              for (int r = 0; r < 4; r++){
                int R = R0 + r;
                if (R < M){
                  int s2 = R / 197, j2 = R - s2 * 197;
                  ((u16*)aux2)[((size_t)(s2 * 12 + (c0 >> 6)) * 64 + (c0 & 63)) * 224
                               + j2 + (s2 & 3)] = f2bf(vv[r]);
                }
              }
            }
          }
        }
      } else {
        #pragma unroll
        for (int r = 0; r < 4; r++){
          const int R = m0 + lrow + r;
          if (R >= M) continue;
          float val = vv[r];
          if constexpr (MODE == 0){
            ((u16*)out)[(size_t)R * ldo + Cg] = f2bf(val);
          } else if constexpr (MODE == 1){
            int Ro = (R / oTs) * oTf + ot0 + (R % oTs);
            u16* po = (u16*)out + (size_t)Ro * ldo + Cg;
            *po = f2bf(0.5f * val + 0.5f * bf2f(*po));
          } else if constexpr (MODE == 2){
            int b_ = R / 3136, m_ = R - b_ * 3136;
            ((u16*)out)[(size_t)R * 768 + Cg] =
                f2bf(val + ((const float*)aux1)[((size_t)b_ * 3137 + 1 + m_) * 768 + Cg]);
          } else if constexpr (MODE == 3){
            int s_ = R / 197, j_ = R - s_ * 197;
            if (j_ == 0){
              ((float*)aux2)[(size_t)s_ * 768 + Cg] = val;
            } else {
              int b_ = s_ >> 4, t_ = s_ & 15, m_ = (j_ - 1) * 16 + t_;
              ((u16*)out)[((size_t)b_ * 3137 + 1 + m_) * 768 + Cg] =
                  f2bf(val + bf2f(((const u16*)aux1)[((size_t)b_ * 3136 + m_) * 768 + Cg]));
            }
          } else if constexpr (MODE == 4){
            // gelu, sigmoid form: x*sigmoid(1.702x); inf-safe; ~6 VALU ops
            float r_ = 1.f / (1.f + __expf(-1.702f * val));
            ((u16*)out)[(size_t)R * ldo + Cg] = f2bf(val * r_);
          } else if constexpr (MODE == 5){
            ((float*)out)[(size_t)R * 768 + Cg] =
                val + bf2f(((const u16*)aux1)[(size_t)R * 768 + Cg]);
          }
        }
      }
    }
  }
}

// ---------------- temporal attention via MFMA: one wave per (seq,head) ----------------
template<int TS, int TSPAD>
__global__ __launch_bounds__(256)
void tattn_k(const u16* __restrict__ q, const u16* __restrict__ k,
             const u16* __restrict__ vt, u16* __restrict__ o){
  const int lane = threadIdx.x & 63;
  const int g = lane >> 4, r16 = lane & 15;
  int p = blockIdx.x * 4 + (threadIdx.x >> 6);
  int seq = p / 12, h = p - seq * 12;

  int trow = (TS < 16 && r16 >= TS) ? TS - 1 : r16;
  size_t qko = (size_t)(seq * TS + trow) * 768 + h * 64 + g * 8;
  bf16x8 ak0 = *(const bf16x8*)(k + qko);
  bf16x8 ak1 = *(const bf16x8*)(k + qko + 32);
  bf16x8 bq0 = *(const bf16x8*)(q + qko);
  bf16x8 bq1 = *(const bf16x8*)(q + qko + 32);

  f32x4 s = {0.f, 0.f, 0.f, 0.f};
  s = __builtin_amdgcn_mfma_f32_16x16x32_bf16(ak0, bq0, s, 0, 0, 0);
  s = __builtin_amdgcn_mfma_f32_16x16x32_bf16(ak1, bq1, s, 0, 0, 0);

  const float C = 0.125f * 1.44269504089f;
  float pv[4]; float mx = -3e38f;
  #pragma unroll
  for (int r = 0; r < 4; r++){
    float x = (g * 4 + r < TS) ? s[r] : -3e38f;
    pv[r] = x; mx = fmaxf(mx, x);
  }
  mx = fmaxf(mx, __shfl_xor(mx, 16));
  mx = fmaxf(mx, __shfl_xor(mx, 32));
  float sum = 0.f;
  #pragma unroll
  for (int r = 0; r < 4; r++){ pv[r] = exp2f((pv[r] - mx) * C); sum += pv[r]; }
  sum += __shfl_xor(sum, 16);
  sum += __shfl_xor(sum, 32);
  float inv = 1.f / sum;
  #pragma unroll
  for (int r = 0; r < 4; r++) pv[r] *= inv;

  u32 w0 = (u32)f2bf(pv[0]) | ((u32)f2bf(pv[1]) << 16);
  u32 w1 = (u32)f2bf(pv[2]) | ((u32)f2bf(pv[3]) << 16);
  int a0 = ((g * 2) * 16 + r16) * 4;
  int a1 = ((g * 2 + 1) * 16 + r16) * 4;
  u32 msk = (g < 2) ? 0xFFFFFFFFu : 0u;
  union { u32 w[4]; bf16x8 v; } pa;
  pa.w[0] = msk & (u32)__builtin_amdgcn_ds_bpermute(a0, (int)w0);
  pa.w[1] = msk & (u32)__builtin_amdgcn_ds_bpermute(a0, (int)w1);
  pa.w[2] = msk & (u32)__builtin_amdgcn_ds_bpermute(a1, (int)w0);
  pa.w[3] = msk & (u32)__builtin_amdgcn_ds_bpermute(a1, (int)w1);

  const u16* vb = vt + ((size_t)(seq * 12 + h) * 64) * TSPAD;
  const f32x4 vz = {0.f, 0.f, 0.f, 0.f};
  f32x4 oc[4];
  #pragma unroll
  for (int dt = 0; dt < 4; ++dt){
    bf16x8 bv = *(const bf16x8*)(vb + (size_t)(dt * 16 + r16) * TSPAD + g * 8);
    oc[dt] = __builtin_amdgcn_mfma_f32_16x16x32_bf16(pa.v, bv, vz, 0, 0, 0);
  }
  #pragma unroll
  for (int rr = 0; rr < 4; ++rr){
    int qr = g * 4 + rr;
    if (qr < TS){
      size_t ob = (size_t)(seq * TS + qr) * 768 + h * 64 + r16;
      #pragma unroll
      for (int dt = 0; dt < 4; ++dt)
        o[ob + dt * 16] = f2bf(oc[dt][rr]);
    }
  }
}

// ---------------- spatial attention: 4 waves/block ----------------
__global__ __launch_bounds__(256)
void sattn_k(const u16* __restrict__ qs, const u16* __restrict__ ks,
             const u16* __restrict__ vt, u16* __restrict__ o){
  __shared__ u16 PlAll[4][16 * 224];
  const int wid = threadIdx.x >> 6;
  u16* Pl = PlAll[wid];
  const int lane = threadIdx.x & 63;
  const int g = lane >> 4, r16 = lane & 15;
  int gi = blockIdx.x * 4 + wid;
  int chunk = gi % 13; int sh_ = gi / 13;
  int h = sh_ % 12, s = sh_ / 12;
  const int shft = s & 3;
  const float sc_l2e = 0.125f * 1.44269504089f;

  #pragma unroll
  for (int i = 0; i < 4; i++){
    Pl[(i * 4 + g) * 224 + 208 + r16] = 0;
    if (r16 < 4) Pl[(i * 4 + g) * 224 + r16] = 0;
  }

  int q0 = chunk * 16;
  int qrow = q0 + r16; if (qrow > 196) qrow = 196;
  const u16* qp = qs + ((size_t)(s * 197 + qrow)) * 768 + h * 64 + g * 8;
  bf16x8 aq0 = *(const bf16x8*)qp;
  bf16x8 aq1 = *(const bf16x8*)(qp + 32);

  f32x4 scv[13];
  #pragma unroll
  for (int jt = 0; jt < 13; ++jt){
    int krow = jt * 16 + r16; if (krow > 196) krow = 196;
    const u16* kp = ks + ((size_t)(s * 197 + krow)) * 768 + h * 64 + g * 8;
    bf16x8 b0 = *(const bf16x8*)kp;
    bf16x8 b1 = *(const bf16x8*)(kp + 32);
    f32x4 z = {0.f, 0.f, 0.f, 0.f};
    z = __builtin_amdgcn_mfma_f32_16x16x32_bf16(aq0, b0, z, 0, 0, 0);
    z = __builtin_amdgcn_mfma_f32_16x16x32_bf16(aq1, b1, z, 0, 0, 0);
    scv[jt] = z;
  }
  float mrow[4] = {-3e38f, -3e38f, -3e38f, -3e38f};
  #pragma unroll
  for (int jt = 0; jt < 13; ++jt)
    #pragma unroll
    for (int r = 0; r < 4; r++){
      float x = (jt * 16 + r16 < 197) ? scv[jt][r] : -3e38f;
      scv[jt][r] = x;
      mrow[r] = fmaxf(mrow[r], x);
    }
  #pragma unroll
  for (int off = 1; off < 16; off <<= 1)
    #pragma unroll
    for (int r = 0; r < 4; r++) mrow[r] = fmaxf(mrow[r], __shfl_xor(mrow[r], off));
  float srow[4] = {0.f, 0.f, 0.f, 0.f};
  #pragma unroll
  for (int jt = 0; jt < 13; ++jt)
    #pragma unroll
    for (int r = 0; r < 4; r++){
      float e = exp2f((scv[jt][r] - mrow[r]) * sc_l2e);
      scv[jt][r] = e;
      srow[r] += e;
    }
  #pragma unroll
  for (int off = 1; off < 16; off <<= 1)
    #pragma unroll
    for (int r = 0; r < 4; r++) srow[r] += __shfl_xor(srow[r], off);
  float inv[4];
  #pragma unroll
  for (int r = 0; r < 4; r++) inv[r] = 1.f / srow[r];
  #pragma unroll
  for (int jt = 0; jt < 13; ++jt)
    #pragma unroll
    for (int r = 0; r < 4; r++)
      Pl[(g * 4 + r) * 224 + jt * 16 + r16 + shft] = f2bf(scv[jt][r] * inv[r]);
  __syncthreads();
  const u16* vbase = vt + ((size_t)(s * 12 + h) * 64) * 224;
  f32x4 oc[4]; const f32x4 vz = {0.f,0.f,0.f,0.f};
  #pragma unroll
  for (int dt = 0; dt < 4; dt++) oc[dt] = vz;
  #pragma unroll
  for (int ks2 = 0; ks2 < 7; ++ks2){
    bf16x8 ap = *(const bf16x8*)(Pl + r16 * 224 + ks2 * 32 + g * 8);
    #pragma unroll
    for (int dt = 0; dt < 4; ++dt){
      const u16* vp = vbase + ((size_t)(dt * 16 + r16)) * 224 + ks2 * 32 + g * 8;
      bf16x8 bv = *(const bf16x8*)vp;
      oc[dt] = __builtin_amdgcn_mfma_f32_16x16x32_bf16(ap, bv, oc[dt], 0, 0, 0);
    }
  }
  #pragma unroll
  for (int dt = 0; dt < 4; ++dt)
    #pragma unroll
    for (int r = 0; r < 4; r++){
      int qr2 = q0 + g * 4 + r;
      if (qr2 < 197)
        o[((size_t)(s * 197 + qr2)) * 768 + h * 64 + dt * 16 + r16] = f2bf(oc[dt][r]);
    }
}

// ======================================================================================
extern "C" void kernel_launch(void* const* d_in, const int* in_sizes, int n_in,
                              void* d_out, int out_size, void* d_ws, size_t ws_size,
                              hipStream_t stream){
  (void)in_sizes; (void)n_in; (void)out_size;
  const float* x    = (const float*)d_in[0];
  const float* ln1g = (const float*)d_in[1];
  const float* ln1b = (const float*)d_in[2];
  const float* tlng = (const float*)d_in[3];
  const float* tlnb = (const float*)d_in[4];
  const float* ln2g = (const float*)d_in[5];
  const float* ln2b = (const float*)d_in[6];
  const float* Ws   = (const float*)d_in[7];
  const float* bs   = (const float*)d_in[8];
  const float* Wt   = (const float*)d_in[9];
  const float* bt   = (const float*)d_in[10];
  const float* Wtp  = (const float*)d_in[11];
  const float* btp  = (const float*)d_in[12];
  const float* Wfc  = (const float*)d_in[13];
  const float* bfc  = (const float*)d_in[14];
  const float* W1   = (const float*)d_in[15];
  const float* b1   = (const float*)d_in[16];
  const float* W2   = (const float*)d_in[17];
  const float* b2   = (const float*)d_in[18];
  float* out = (float*)d_out;

  constexpr size_t MiB = 1048576;
  constexpr size_t C2  = 589824;
  constexpr size_t W_BYTES = (17 * C2 + 2 * 2359296) * 2;  // 29,491,200
  constexpr size_t NEED = W_BYTES + 143 * MiB;
  if (ws_size < NEED) return;

  char* wsb  = (char*)d_ws;
  u16*  wbuf = (u16*)wsb;
  u16*  W1T  = wbuf + 17 * C2;
  u16*  W2T  = W1T + (size_t)3072 * 768;
  char* A0   = wsb + W_BYTES;

  u16*  ht  = (u16*)(A0 + 0   * MiB);
  u16*  qk  = (u16*)(A0 + 20  * MiB);
  u16*  vtb = (u16*)(A0 + 58  * MiB);
  u16*  o16 = (u16*)(A0 + 86  * MiB);
  u16*  o8  = (u16*)(A0 + 105 * MiB);
  u16*  o4  = (u16*)(A0 + 115 * MiB);
  u16*  xt2 = (u16*)(A0 + 105 * MiB);
  u16*  xnb = (u16*)(A0 + 20 * MiB);
  u16*  wtp2b = (u16*)(A0 + 132 * MiB);
  u16*  WpT   = (u16*)(A0 + 134 * MiB);
  float* bprime = (float*)(A0 + 136 * MiB);
  float* zb     = bprime + 1024;
  float* clsb = (float*)(A0 + 142 * MiB);
  u16*  hs  = ht;  u16* osb = ht; u16* h2 = ht;
  u16*  a1  = (u16*)(A0 + 58 * MiB);

  // -- fused weight prep + temporal LN, bias fold, W' GEMM
  wprep_k<<<18112, 256, 0, stream>>>(Ws, Wt, Wtp, Wfc, wbuf, W1, W1T, W2, W2T,
                                     wtp2b, x, tlng, tlnb, ht);
  bprep_k<<<192, 256, 0, stream>>>(btp + 1536, wbuf + 16*C2, bfc, bprime, zb);
  gemm_k<0,2><<<12*6, 256, 0, stream>>>(wbuf + 16*C2, wtp2b, zb, WpT, nullptr, nullptr, 6, 768, 768, 768, 768, 1,1,0, 1,1,0);

  // -- scale 16: fused QKV + attn  [BIG tile]
  gemm_k<8,1><<<49*18, 512, 0, stream>>>(ht, wbuf + 10*C2, bt + 6*768, qk, nullptr, vtb, 18, 12544, 768, 768, 24, 1,1,0, 16,1,12544);
  tattn_k<16,24><<<2352, 256, 0, stream>>>(qk, qk + (size_t)12544*768, vtb, o16);

  // -- scale 8  [128 tile]
  gemm_k<8,0><<<49*18, 256, 0, stream>>>(ht, wbuf +  7*C2, bt + 3*768, qk, nullptr, vtb, 18, 6272, 768, 768, 16, 8,16,8, 8,1,6272);
  tattn_k< 8,16><<<2352, 256, 0, stream>>>(qk, qk + (size_t)6272*768, vtb, o8);

  // -- scale 4  [128 tile]
  gemm_k<8,0><<<25*18, 256, 0, stream>>>(ht, wbuf +  4*C2, bt + 0*768, qk, nullptr, vtb, 18, 3136, 768, 768, 16, 4,16,12, 4,1,3136);
  tattn_k< 4,16><<<2352, 256, 0, stream>>>(qk, qk + (size_t)3136*768, vtb, o4);

  // -- blend chain + collapsed xt2  [thin 64 tile: small-K grid-starved]
  gemm_k<1,2><<<49*6, 256, 0, stream>>>(o4,  wbuf + 13*C2, btp + 0,   o8,  nullptr, nullptr, 6, 3136, 768, 768, 768, 1,1,0, 4,8,4);
  gemm_k<1,2><<<98*6, 256, 0, stream>>>(o8,  wbuf + 14*C2, btp + 768, o16, nullptr, nullptr, 6, 6272, 768, 768, 768, 1,1,0, 8,16,8);
  gemm_k<2,2><<<196*6, 256, 0, stream>>>(o16, WpT,         bprime,    xt2, x, nullptr,       6, 12544, 768, 768, 768, 1,1,0, 1,1,0);

  // -- spatial LN + vT zero-fill, fused QKV  [BIG tile]
  lnfz_k<<<5200, 256, 0, stream>>>(x, xt2, ln1g, ln1b, hs, (u32*)vtb, 5505024);
  gemm_k<9,1><<<50*18, 512, 0, stream>>>(hs, wbuf + 0*C2, bs + 0, qk, nullptr, vtb, 18, 12608, 768, 768, 224, 1,1,0, 1,1,12608);

  // -- spatial attention
  sattn_k<<<2496, 256, 0, stream>>>(qk, qk + (size_t)12608*768, vtb, osb);

  // -- spatial proj + residual scatter  [thin tile, K=768]
  gemm_k<3,2><<<197*6, 256, 0, stream>>>(osb, wbuf + 3*C2, bs + 2304, xnb, xt2, clsb, 6, 12608, 768, 768, 768, 1,1,0, 1,1,0);

  // -- final LN (with inlined cls finish) + MLP  [up: BIG; down: 128 tile]
  ln2_k<<<3137, 256, 0, stream>>>(xnb, ln2g, ln2b, h2, x, clsb);
  gemm_k<4,1><<<50*24, 512, 0, stream>>>(h2, W1T, b1, a1,  nullptr, nullptr, 24, 12548, 768, 768, 3072, 1,1,0, 1,1,0);
  gemm_k<5,0><<<99*6, 256, 0, stream>>>(a1, W2T, b2, out, xnb, nullptr,      6, 12548, 3072, 3072, 768, 1,1,0, 1,1,0);
}